// Round 15
// baseline (318.919 us; speedup 1.0000x reference)
//
#include <hip/hip_runtime.h>
#include <hip/hip_bf16.h>

#define NN  100000
#define D   64
#define KS  20
#define DFF 256
#define EPS 1e-5f

// radix-partition params
#define BROWS  512
#define NB     ((NN + BROWS - 1) / BROWS)   // 196 buckets
#define PCHUNK 8192                          // edges per chunk (k_bhist & k_part)

// frag-buffer offsets (shorts)
#define OFF_W1 0
#define OFF_W2 16384
#define OFF_WG 32768
#define OFF_WQ 40960
#define OFF_WK 45056
#define OFF_WV 49152
#define OFF_WO 53248
#define S_TOTAL 57344

typedef __attribute__((ext_vector_type(8))) short bf16x8;
typedef __attribute__((ext_vector_type(4))) float f32x4;

__device__ __forceinline__ short f2b(float f) {
    return __builtin_bit_cast(short, __float2bfloat16(f));
}
__device__ __forceinline__ unsigned short f2bu(float f) {
    return __builtin_bit_cast(unsigned short, __float2bfloat16(f));
}
__device__ __forceinline__ float b2f(unsigned short u) {
    return __builtin_bit_cast(float, ((unsigned)u) << 16);
}
__device__ __forceinline__ unsigned char f2fp8(float v) {
    int p = __builtin_amdgcn_cvt_pk_fp8_f32(v, v, 0, false);
    return (unsigned char)(p & 0xFF);
}
// fp4 e2m1 encode: grid {0,.5,1,1.5,2,3,4,6}, RNE via midpoint thresholds
__device__ __forceinline__ unsigned f4code(float v) {
    float a = fabsf(v);
    unsigned c = (unsigned)(a >= 0.25f) + (a >= 0.75f) + (a >= 1.25f) + (a >= 1.75f)
               + (a >= 2.5f) + (a >= 3.5f) + (a >= 5.0f);
    return c | (v < 0.f ? 8u : 0u);
}
// decode 4 fp4 (one ushort) -> 4 floats via nibble-spread + v_perm fp4->fp8 table + HW cvt
__device__ __forceinline__ void f4dec(unsigned short u, float& x, float& y, float& z, float& w) {
    unsigned t = u;
    t = (t | (t << 8)) & 0x00FF00FFu;
    t = (t | (t << 4)) & 0x0F0F0F0Fu;           // bytes = nibbles n0..n3
    unsigned sel = t & 0x07070707u;
    unsigned sgn = (t & 0x08080808u) << 4;
    unsigned f8 = __builtin_amdgcn_perm(0x4C484440u, 0x3C383000u, sel) | sgn;
    x = __builtin_amdgcn_cvt_f32_fp8(f8, 0);
    y = __builtin_amdgcn_cvt_f32_fp8(f8, 1);
    z = __builtin_amdgcn_cvt_f32_fp8(f8, 2);
    w = __builtin_amdgcn_cvt_f32_fp8(f8, 3);
}
__device__ __forceinline__ float gsum16(float v) {
    v += __shfl_xor(v, 1, 64);
    v += __shfl_xor(v, 2, 64);
    v += __shfl_xor(v, 4, 64);
    v += __shfl_xor(v, 8, 64);
    return v;
}

// ---------------- weight fragment prep (bf16, B-operand layout) ----------------
__global__ __launch_bounds__(256) void k_prep(
    const float* __restrict__ W1, const float* __restrict__ W2,
    const float* __restrict__ Wg,
    const float* __restrict__ Wq, const float* __restrict__ Wk,
    const float* __restrict__ Wv, const float* __restrict__ Wo,
    short* __restrict__ S)
{
    int idx = blockIdx.x * 256 + threadIdx.x;
    for (; idx < S_TOTAL; idx += gridDim.x * 256) {
        float v;
        if (idx < OFF_W2) {                 // W1 [64 x 256]
            int f = idx >> 9, rem = idx & 511;
            int l = rem >> 3, i = rem & 7;
            int nt = f >> 1, kt = f & 1;
            v = W1[(kt * 32 + (l >> 4) * 8 + i) * DFF + nt * 16 + (l & 15)];
        } else if (idx < OFF_WG) {          // W2 [256 x 64]
            int j = idx - OFF_W2;
            int f = j >> 9, rem = j & 511;
            int l = rem >> 3, i = rem & 7;
            int nt = f >> 3, kt = f & 7;
            v = W2[(kt * 32 + (l >> 4) * 8 + i) * D + nt * 16 + (l & 15)];
        } else if (idx < OFF_WQ) {          // Wg [128 x 64]
            int j = idx - OFF_WG;
            int f = j >> 9, rem = j & 511;
            int l = rem >> 3, i = rem & 7;
            int nt = f >> 2, kt = f & 3;
            v = Wg[(kt * 32 + (l >> 4) * 8 + i) * D + nt * 16 + (l & 15)];
        } else {                            // Wq/Wk/Wv/Wo [64 x 64]
            int j = idx - OFF_WQ;
            const float* W = (j < 4096) ? Wq : (j < 8192) ? Wk : (j < 12288) ? Wv : Wo;
            j &= 4095;
            int f = j >> 9, rem = j & 511;
            int l = rem >> 3, i = rem & 7;
            int nt = f >> 1, kt = f & 1;
            v = W[(kt * 32 + (l >> 4) * 8 + i) * D + nt * 16 + (l & 15)];
        }
        S[idx] = f2b(v);
    }
}

// ---------------- per-chunk bucket histogram (dense write, NO global atomics) ----------------
__global__ __launch_bounds__(256) void k_bhist(
    const int* __restrict__ rows, int* __restrict__ partial, int E)
{
    __shared__ int h[NB];
    for (int t = threadIdx.x; t < NB; t += 256) h[t] = 0;
    __syncthreads();
    const int i0 = blockIdx.x * PCHUNK;
    const int n = min(PCHUNK, E - i0);
    for (int t = threadIdx.x; t < n; t += 256)
        atomicAdd(&h[__builtin_nontemporal_load(rows + i0 + t) >> 9], 1);
    __syncthreads();
    for (int t = threadIdx.x; t < NB; t += 256)
        partial[blockIdx.x * NB + t] = h[t];
}

// ---------------- parallel 2D prefix, stage A: per-bucket scan over chunks ----------------
__global__ __launch_bounds__(256) void k_pscan_a(
    int* __restrict__ partial, int* __restrict__ btot, int npb)
{
    __shared__ int wsum[4];
    __shared__ int s_carry;
    const int b = blockIdx.x;
    const int tid = threadIdx.x;
    const int lane = tid & 63, wv = tid >> 6;
    if (tid == 0) s_carry = 0;
    __syncthreads();
    for (int base = 0; base < npb; base += 512) {
        int p0 = base + 2 * tid, p1 = p0 + 1;
        int c0 = (p0 < npb) ? partial[p0 * NB + b] : 0;
        int c1 = (p1 < npb) ? partial[p1 * NB + b] : 0;
        int s = c0 + c1;
        int sv = s;
        #pragma unroll
        for (int off = 1; off < 64; off <<= 1) {
            int u = __shfl_up(sv, off, 64);
            if (lane >= off) sv += u;
        }
        if (lane == 63) wsum[wv] = sv;
        __syncthreads();
        int wofs = 0;
        for (int k = 0; k < wv; ++k) wofs += wsum[k];
        int o0 = s_carry + wofs + sv - s;
        int o1 = o0 + c0;
        if (p0 < npb) partial[p0 * NB + b] = o0;
        if (p1 < npb) partial[p1 * NB + b] = o1;
        __syncthreads();
        if (tid == 0) s_carry += wsum[0] + wsum[1] + wsum[2] + wsum[3];
        __syncthreads();
    }
    if (tid == 0) btot[b] = s_carry;
}

// ---------------- stage B: bucket scan of totals -> bbase; offsets[NN]=E ----------------
__global__ __launch_bounds__(256) void k_pscan_b(
    const int* __restrict__ btot, int* __restrict__ bbase,
    int* __restrict__ offsets)
{
    __shared__ int wsum[4];
    const int t = threadIdx.x;
    const int lane = t & 63, wv = t >> 6;
    int v = (t < NB) ? btot[t] : 0;
    int sv = v;
    #pragma unroll
    for (int off = 1; off < 64; off <<= 1) {
        int u = __shfl_up(sv, off, 64);
        if (lane >= off) sv += u;
    }
    if (lane == 63) wsum[wv] = sv;
    __syncthreads();
    int wofs = 0;
    for (int k = 0; k < wv; ++k) wofs += wsum[k];
    int excl = wofs + sv - v;
    if (t < NB) bbase[t] = excl;
    if (t == 0) {
        int tot = wsum[0] + wsum[1] + wsum[2] + wsum[3];
        bbase[NB] = tot;
        offsets[NN] = tot;
    }
}

// ---------------- phase 1: radix-partition edges by bucket (row>>9) ----------------
__global__ __launch_bounds__(256) void k_part(
    const int* __restrict__ rows, const int* __restrict__ cols,
    const float* __restrict__ ev, const int* __restrict__ pbase,
    const int* __restrict__ bbase,
    int2* __restrict__ part, int E)
{
    __shared__ int base[NB];
    __shared__ int lcnt[NB];
    const int tid = threadIdx.x;
    const int i0 = blockIdx.x * PCHUNK;
    const int n = min(PCHUNK, E - i0);
    for (int t = tid; t < NB; t += 256) {
        base[t] = bbase[t] + pbase[blockIdx.x * NB + t];
        lcnt[t] = 0;
    }
    __syncthreads();
    for (int t = tid; t < n; t += 256) {
        int r = __builtin_nontemporal_load(rows + i0 + t);
        int c = __builtin_nontemporal_load(cols + i0 + t);
        float w = __builtin_nontemporal_load(ev + i0 + t);
        int b = r >> 9;
        int lpos = atomicAdd(&lcnt[b], 1);
        part[base[b] + lpos] = make_int2(((r & (BROWS - 1)) << 17) | c, __float_as_int(w));
    }
}

// ---------------- phase 2: in-bucket row offsets (LDS scan) + packed placement ----------------
// payload: (col << 15) | (bf16(w) & 0x7FFF)  -- w in [0,1) so sign bit is 0
__global__ __launch_bounds__(256) void k_fill2(
    const int* __restrict__ bbase, const int2* __restrict__ part,
    int* __restrict__ offsets, unsigned int* __restrict__ payload)
{
    __shared__ int lcnt[BROWS];
    __shared__ int lcur[BROWS];
    __shared__ int wsum[4];
    const int b = blockIdx.x;
    const int row0 = b * BROWS;
    const int nrows = min(BROWS, NN - row0);
    const int tid = threadIdx.x;
    for (int t = tid; t < BROWS; t += 256) lcnt[t] = 0;
    __syncthreads();
    const int e0 = bbase[b], e1 = bbase[b + 1];
    for (int i = e0 + tid; i < e1; i += 256)
        atomicAdd(&lcnt[(unsigned)part[i].x >> 17], 1);
    __syncthreads();
    int c0 = lcnt[2 * tid], c1 = lcnt[2 * tid + 1];
    int s = c0 + c1;
    const int lane = tid & 63, wv = tid >> 6;
    int sv = s;
    #pragma unroll
    for (int off = 1; off < 64; off <<= 1) {
        int u = __shfl_up(sv, off, 64);
        if (lane >= off) sv += u;
    }
    if (lane == 63) wsum[wv] = sv;
    __syncthreads();
    int wofs = 0;
    for (int k = 0; k < wv; ++k) wofs += wsum[k];
    int o0 = e0 + wofs + sv - s;
    int o1 = o0 + c0;
    lcur[2 * tid] = o0;
    lcur[2 * tid + 1] = o1;
    if (2 * tid < nrows)     offsets[row0 + 2 * tid]     = o0;
    if (2 * tid + 1 < nrows) offsets[row0 + 2 * tid + 1] = o1;
    __syncthreads();
    for (int i = e0 + tid; i < e1; i += 256) {
        int2 rec = part[i];
        int rowoff = (unsigned)rec.x >> 17;
        int pos = atomicAdd(&lcur[rowoff], 1);
        unsigned int col = (unsigned)(rec.x & 0x1FFFF);
        unsigned int wb = (unsigned)(f2bu(__int_as_float(rec.y)) & 0x7FFF);
        payload[pos] = (col << 15) | wb;
    }
}

// ---------------- segment gather-reduce (fp4 source, packed payload) ----------------
__global__ __launch_bounds__(256) void k_gather(
    const int* __restrict__ offsets, const unsigned int* __restrict__ payload,
    const unsigned char* __restrict__ h2f4, unsigned short* __restrict__ hnb)
{
    const int lane = threadIdx.x & 63;
    const int g = lane >> 4, c0 = lane & 15;
    int w = (blockIdx.x * 256 + threadIdx.x) >> 6;
    const int nw = (gridDim.x * 256) >> 6;
    for (int row = w; row < NN; row += nw) {
        const int b = offsets[row], e = offsets[row + 1];
        float ax = 0.f, ay = 0.f, az = 0.f, aw = 0.f;
        int i = b + g;
        for (; i + 4 < e; i += 8) {
            unsigned int p0 = __builtin_nontemporal_load(payload + i);
            unsigned int p1 = __builtin_nontemporal_load(payload + i + 4);
            float w0 = b2f((unsigned short)(p0 & 0x7FFF));
            float w1 = b2f((unsigned short)(p1 & 0x7FFF));
            unsigned short u0 = *(const unsigned short*)(h2f4 + (size_t)(p0 >> 15) * 32 + c0 * 2);
            unsigned short u1 = *(const unsigned short*)(h2f4 + (size_t)(p1 >> 15) * 32 + c0 * 2);
            float x0, y0, z0, v0, x1, y1, z1, v1;
            f4dec(u0, x0, y0, z0, v0);
            f4dec(u1, x1, y1, z1, v1);
            ax = fmaf(x0, w0, ax); ay = fmaf(y0, w0, ay);
            az = fmaf(z0, w0, az); aw = fmaf(v0, w0, aw);
            ax = fmaf(x1, w1, ax); ay = fmaf(y1, w1, ay);
            az = fmaf(z1, w1, az); aw = fmaf(v1, w1, aw);
        }
        if (i < e) {
            unsigned int p = __builtin_nontemporal_load(payload + i);
            float wt = b2f((unsigned short)(p & 0x7FFF));
            unsigned short u = *(const unsigned short*)(h2f4 + (size_t)(p >> 15) * 32 + c0 * 2);
            float x0, y0, z0, v0;
            f4dec(u, x0, y0, z0, v0);
            ax = fmaf(x0, wt, ax); ay = fmaf(y0, wt, ay);
            az = fmaf(z0, wt, az); aw = fmaf(v0, wt, aw);
        }
        ax += __shfl_xor(ax, 16, 64); ax += __shfl_xor(ax, 32, 64);
        ay += __shfl_xor(ay, 16, 64); ay += __shfl_xor(ay, 32, 64);
        az += __shfl_xor(az, 16, 64); az += __shfl_xor(az, 32, 64);
        aw += __shfl_xor(aw, 16, 64); aw += __shfl_xor(aw, 32, 64);
        if (g == 0) {
            ushort4 o;
            o.x = f2bu(ax); o.y = f2bu(ay); o.z = f2bu(az); o.w = f2bu(aw);
            *(ushort4*)(hnb + (size_t)row * 64 + c0 * 4) = o;
        }
    }
}

// ---------------- Q/K/V projection via MFMA -> Q bf16, KV interleaved fp8 ----------------
__global__ __launch_bounds__(256) void k_projqkv_mfma(
    const float* __restrict__ x, const short* __restrict__ S,
    const float* __restrict__ bq, const float* __restrict__ bk,
    const float* __restrict__ bv,
    unsigned short* __restrict__ Qp, unsigned char* __restrict__ KV8)
{
    const int lane = threadIdx.x & 63;
    const int c0 = lane & 15;
    const int g  = lane >> 4;
    const bf16x8* wq = (const bf16x8*)(S + OFF_WQ);
    const bf16x8* wk = (const bf16x8*)(S + OFF_WK);
    const bf16x8* wv = (const bf16x8*)(S + OFF_WV);

    float bqv[4], bkv[4], bvv[4];
    #pragma unroll
    for (int nt = 0; nt < 4; ++nt) {
        bqv[nt] = bq[nt * 16 + c0];
        bkv[nt] = bk[nt * 16 + c0];
        bvv[nt] = bv[nt * 16 + c0];
    }

    int wid = (blockIdx.x * 256 + threadIdx.x) >> 6;
    const int nwaves = (gridDim.x * 256) >> 6;
    for (int tile = wid; tile < NN / 16; tile += nwaves) {
        const int row0 = tile * 16;
        const float* ar = x + (size_t)(row0 + c0) * D + g * 8;
        bf16x8 a0, a1;
        {
            float4 f0 = *(const float4*)(ar);
            float4 f1 = *(const float4*)(ar + 4);
            float4 f2 = *(const float4*)(ar + 32);
            float4 f3 = *(const float4*)(ar + 36);
            a0[0] = f2b(f0.x); a0[1] = f2b(f0.y); a0[2] = f2b(f0.z); a0[3] = f2b(f0.w);
            a0[4] = f2b(f1.x); a0[5] = f2b(f1.y); a0[6] = f2b(f1.z); a0[7] = f2b(f1.w);
            a1[0] = f2b(f2.x); a1[1] = f2b(f2.y); a1[2] = f2b(f2.z); a1[3] = f2b(f2.w);
            a1[4] = f2b(f3.x); a1[5] = f2b(f3.y); a1[6] = f2b(f3.z); a1[7] = f2b(f3.w);
        }
        f32x4 aq[4], ak[4], av[4];
        #pragma unroll
        for (int nt = 0; nt < 4; ++nt) {
            f32x4 cq = {bqv[nt], bqv[nt], bqv[nt], bqv[nt]};
            cq = __builtin_amdgcn_mfma_f32_16x16x32_bf16(a0, wq[(nt * 2 + 0) * 64 + lane], cq, 0, 0, 0);
            cq = __builtin_amdgcn_mfma_f32_16x16x32_bf16(a1, wq[(nt * 2 + 1) * 64 + lane], cq, 0, 0, 0);
            aq[nt] = cq;
            f32x4 ck = {bkv[nt], bkv[nt], bkv[nt], bkv[nt]};
            ck = __builtin_amdgcn_mfma_f32_16x16x32_bf16(a0, wk[(nt * 2 + 0) * 64 + lane], ck, 0, 0, 0);
            ck = __builtin_amdgcn_mfma_f32_16x16x32_bf16(a1, wk[(nt * 2 + 1) * 64 + lane], ck, 0, 0, 0);
            ak[nt] = ck;
            f32x4 cv = {bvv[nt], bvv[nt], bvv[nt], bvv[nt]};
            cv = __builtin_amdgcn_mfma_f32_16x16x32_bf16(a0, wv[(nt * 2 + 0) * 64 + lane], cv, 0, 0, 0);
            cv = __builtin_amdgcn_mfma_f32_16x16x32_bf16(a1, wv[(nt * 2 + 1) * 64 + lane], cv, 0, 0, 0);
            av[nt] = cv;
        }
        const int r0 = row0 + g * 4;
        #pragma unroll
        for (int r = 0; r < 4; ++r) {
            #pragma unroll
            for (int nt = 0; nt < 4; ++nt) {
                Qp[(size_t)(r0 + r) * D + nt * 16 + c0] = f2bu(aq[nt][r]);
                KV8[(size_t)(r0 + r) * 128 + nt * 16 + c0]      = f2fp8(ak[nt][r]);
                KV8[(size_t)(r0 + r) * 128 + 64 + nt * 16 + c0] = f2fp8(av[nt][r]);
            }
        }
    }
}

// ---------------- attention core: interleaved fp8 KV gathers + per-head softmax + PV ----------------
__global__ __launch_bounds__(256) void k_attn_lite(
    const unsigned short* __restrict__ Qp,
    const unsigned char* __restrict__ KV8,
    const int* __restrict__ samp, unsigned short* __restrict__ ob)
{
    const int lane = threadIdx.x & 63;
    const int g = lane >> 4, c0 = lane & 15;
    int w = (blockIdx.x * 256 + threadIdx.x) >> 6;
    const int nw = (gridDim.x * 256) >> 6;
    for (int row = w; row < NN; row += nw) {
        int idx_reg = (lane < KS) ? samp[row * KS + lane] : 0;
        const ushort4 qv = *(const ushort4*)(Qp + (size_t)row * D + c0 * 4);
        float q0 = b2f(qv.x), q1 = b2f(qv.y), q2 = b2f(qv.z), q3 = b2f(qv.w);

        float s[5];
        int v4[5];
        #pragma unroll
        for (int t = 0; t < 5; ++t) {
            int idx = __shfl(idx_reg, g * 5 + t, 64);
            const unsigned char* base = KV8 + (size_t)idx * 128 + c0 * 4;
            const int ku = *(const int*)(base);
            v4[t] = *(const int*)(base + 64);
            float sc = q0 * __builtin_amdgcn_cvt_f32_fp8(ku, 0);
            sc = fmaf(q1, __builtin_amdgcn_cvt_f32_fp8(ku, 1), sc);
            sc = fmaf(q2, __builtin_amdgcn_cvt_f32_fp8(ku, 2), sc);
            sc = fmaf(q3, __builtin_amdgcn_cvt_f32_fp8(ku, 3), sc);
            sc += __shfl_xor(sc, 1, 64);
            sc += __shfl_xor(sc, 2, 64);
            s[t] = sc * 0.25f;   // 1/sqrt(DH=16)
        }
        float m = fmaxf(fmaxf(fmaxf(s[0], s[1]), fmaxf(s[2], s[3])), s[4]);
        m = fmaxf(m, __shfl_xor(m, 16, 64));
        m = fmaxf(m, __shfl_xor(m, 32, 64));
        float o0 = 0.f, o1 = 0.f, o2 = 0.f, o3 = 0.f, ssum = 0.f;
        #pragma unroll
        for (int t = 0; t < 5; ++t) {
            float p = __expf(s[t] - m);
            ssum += p;
            o0 = fmaf(p, __builtin_amdgcn_cvt_f32_fp8(v4[t], 0), o0);
            o1 = fmaf(p, __builtin_amdgcn_cvt_f32_fp8(v4[t], 1), o1);
            o2 = fmaf(p, __builtin_amdgcn_cvt_f32_fp8(v4[t], 2), o2);
            o3 = fmaf(p, __builtin_amdgcn_cvt_f32_fp8(v4[t], 3), o3);
        }
        ssum += __shfl_xor(ssum, 16, 64);
        ssum += __shfl_xor(ssum, 32, 64);
        float inv = 1.0f / ssum;
        o0 += __shfl_xor(o0, 16, 64); o0 += __shfl_xor(o0, 32, 64);
        o1 += __shfl_xor(o1, 16, 64); o1 += __shfl_xor(o1, 32, 64);
        o2 += __shfl_xor(o2, 16, 64); o2 += __shfl_xor(o2, 32, 64);
        o3 += __shfl_xor(o3, 16, 64); o3 += __shfl_xor(o3, 32, 64);
        if (g == 0) {
            ushort4 o;
            o.x = f2bu(o0 * inv); o.y = f2bu(o1 * inv);
            o.z = f2bu(o2 * inv); o.w = f2bu(o3 * inv);
            *(ushort4*)(ob + (size_t)row * D + c0 * 4) = o;
        }
    }
}

// ---------------- Wo projection + residual + LN1 via MFMA -> hb fp32 ----------------
__global__ __launch_bounds__(256) void k_attno_mfma(
    const unsigned short* __restrict__ ob, const float* __restrict__ x,
    const short* __restrict__ S,
    const float* __restrict__ bo, const float* __restrict__ g1,
    const float* __restrict__ be1,
    float* __restrict__ hb)
{
    const int lane = threadIdx.x & 63;
    const int c0 = lane & 15;
    const int g  = lane >> 4;
    const bf16x8* wp = (const bf16x8*)(S + OFF_WO);

    float bov[4], g1v[4], b1v[4];
    #pragma unroll
    for (int nt = 0; nt < 4; ++nt) {
        bov[nt] = bo[nt * 16 + c0];
        g1v[nt] = g1[nt * 16 + c0];
        b1v[nt] = be1[nt * 16 + c0];
    }

    int wid = (blockIdx.x * 256 + threadIdx.x) >> 6;
    const int nwaves = (gridDim.x * 256) >> 6;
    for (int tile = wid; tile < NN / 16; tile += nwaves) {
        const int row0 = tile * 16;
        bf16x8 a[2];
        #pragma unroll
        for (int kt = 0; kt < 2; ++kt)
            a[kt] = *(const bf16x8*)&ob[(size_t)(row0 + c0) * D + kt * 32 + g * 8];
        f32x4 acc[4];
        #pragma unroll
        for (int nt = 0; nt < 4; ++nt) {
            f32x4 c = {bov[nt], bov[nt], bov[nt], bov[nt]};
            #pragma unroll
            for (int kt = 0; kt < 2; ++kt)
                c = __builtin_amdgcn_mfma_f32_16x16x32_bf16(a[kt], wp[(nt * 2 + kt) * 64 + lane], c, 0, 0, 0);
            acc[nt] = c;
        }
        const int r0 = row0 + g * 4;
        #pragma unroll
        for (int r = 0; r < 4; ++r) {
            float rv[4];
            float s = 0.f;
            #pragma unroll
            for (int nt = 0; nt < 4; ++nt) {
                rv[nt] = acc[nt][r] + x[(size_t)(r0 + r) * D + nt * 16 + c0];
                s += rv[nt];
            }
            s = gsum16(s);
            float mu = s * (1.f / 64.f);
            float q = 0.f;
            #pragma unroll
            for (int nt = 0; nt < 4; ++nt) { float d = rv[nt] - mu; q += d * d; }
            q = gsum16(q);
            float inv = rsqrtf(q * (1.f / 64.f) + EPS);
            #pragma unroll
            for (int nt = 0; nt < 4; ++nt)
                hb[(size_t)(r0 + r) * D + nt * 16 + c0] = (rv[nt] - mu) * inv * g1v[nt] + b1v[nt];
        }
    }
}

// ---------------- FFN via MFMA -> bf16 h2 + fp4 copy ----------------
__global__ __launch_bounds__(256) void k_ffn_mfma(
    const float* __restrict__ hb,
    const short* __restrict__ wf,
    const float* __restrict__ bf1, const float* __restrict__ bf2,
    const float* __restrict__ g2, const float* __restrict__ be2,
    unsigned short* __restrict__ h2b, unsigned char* __restrict__ h2f4)
{
    __shared__ __align__(16) short Tl[4][16][264];
    const int lane = threadIdx.x & 63;
    const int wv   = threadIdx.x >> 6;
    const int c0   = lane & 15;
    const int g    = lane >> 4;
    const bf16x8* w1p = (const bf16x8*)(wf + OFF_W1);
    const bf16x8* w2p = (const bf16x8*)(wf + OFF_W2);

    float b1v[16];
    #pragma unroll
    for (int nt = 0; nt < 16; ++nt) b1v[nt] = bf1[nt * 16 + c0];
    float b2v[4], g2v[4], bev[4];
    #pragma unroll
    for (int nt = 0; nt < 4; ++nt) {
        b2v[nt] = bf2[nt * 16 + c0];
        g2v[nt] = g2[nt * 16 + c0];
        bev[nt] = be2[nt * 16 + c0];
    }

    int wid = (blockIdx.x * 256 + threadIdx.x) >> 6;
    const int nwaves = (gridDim.x * 256) >> 6;
    for (int tile = wid; tile < NN / 16; tile += nwaves) {
        const int row0 = tile * 16;
        const float* ar = hb + (size_t)(row0 + c0) * D + g * 8;
        bf16x8 a0, a1;
        {
            float4 f0 = *(const float4*)(ar);
            float4 f1 = *(const float4*)(ar + 4);
            float4 f2 = *(const float4*)(ar + 32);
            float4 f3 = *(const float4*)(ar + 36);
            a0[0] = f2b(f0.x); a0[1] = f2b(f0.y); a0[2] = f2b(f0.z); a0[3] = f2b(f0.w);
            a0[4] = f2b(f1.x); a0[5] = f2b(f1.y); a0[6] = f2b(f1.z); a0[7] = f2b(f1.w);
            a1[0] = f2b(f2.x); a1[1] = f2b(f2.y); a1[2] = f2b(f2.z); a1[3] = f2b(f2.w);
            a1[4] = f2b(f3.x); a1[5] = f2b(f3.y); a1[6] = f2b(f3.z); a1[7] = f2b(f3.w);
        }
        f32x4 acc1[16];
        #pragma unroll
        for (int nt = 0; nt < 16; ++nt) {
            float b = b1v[nt];
            f32x4 c = {b, b, b, b};
            c = __builtin_amdgcn_mfma_f32_16x16x32_bf16(a0, w1p[(nt * 2 + 0) * 64 + lane], c, 0, 0, 0);
            c = __builtin_amdgcn_mfma_f32_16x16x32_bf16(a1, w1p[(nt * 2 + 1) * 64 + lane], c, 0, 0, 0);
            acc1[nt] = c;
        }
        #pragma unroll
        for (int nt = 0; nt < 16; ++nt) {
            #pragma unroll
            for (int r = 0; r < 4; ++r)
                Tl[wv][g * 4 + r][nt * 16 + c0] = f2b(fmaxf(acc1[nt][r], 0.f));
        }
        bf16x8 a2[8];
        #pragma unroll
        for (int kt = 0; kt < 8; ++kt)
            a2[kt] = *(const bf16x8*)&Tl[wv][c0][kt * 32 + g * 8];
        f32x4 acc2[4];
        #pragma unroll
        for (int nt = 0; nt < 4; ++nt) {
            float b = b2v[nt];
            f32x4 c = {b, b, b, b};
            #pragma unroll
            for (int kt = 0; kt < 8; ++kt)
                c = __builtin_amdgcn_mfma_f32_16x16x32_bf16(a2[kt], w2p[(nt * 8 + kt) * 64 + lane], c, 0, 0, 0);
            acc2[nt] = c;
        }
        const int r0 = row0 + g * 4;
        #pragma unroll
        for (int r = 0; r < 4; ++r) {
            float rv[4];
            float s = 0.f;
            #pragma unroll
            for (int nt = 0; nt < 4; ++nt) {
                rv[nt] = acc2[nt][r] + hb[(size_t)(r0 + r) * D + nt * 16 + c0];
                s += rv[nt];
            }
            s = gsum16(s);
            float mu = s * (1.f / 64.f);
            float q = 0.f;
            #pragma unroll
            for (int nt = 0; nt < 4; ++nt) { float d = rv[nt] - mu; q += d * d; }
            q = gsum16(q);
            float inv = rsqrtf(q * (1.f / 64.f) + EPS);
            unsigned pcode = 0;
            #pragma unroll
            for (int nt = 0; nt < 4; ++nt) {
                float hv = (rv[nt] - mu) * inv * g2v[nt] + bev[nt];
                h2b[(size_t)(r0 + r) * D + nt * 16 + c0] = f2bu(hv);
                pcode |= f4code(hv) << (8 * nt);
            }
            unsigned qcode = (unsigned)__shfl_xor((int)pcode, 1, 64);
            if (!(lane & 1)) {
                #pragma unroll
                for (int nt = 0; nt < 4; ++nt) {
                    unsigned byte = ((pcode >> (8 * nt)) & 0xF) | (((qcode >> (8 * nt)) & 0xF) << 4);
                    h2f4[(size_t)(r0 + r) * 32 + nt * 8 + (c0 >> 1)] = (unsigned char)byte;
                }
            }
        }
    }
}

// ---------------- GNN linear (MFMA, bf16 inputs) + relu + residual + LN -> fp32 out ----------------
__global__ __launch_bounds__(256) void k_gnn_mfma(
    const unsigned short* __restrict__ h2b, const unsigned short* __restrict__ hnb,
    const short* __restrict__ S,
    const float* __restrict__ bg, const float* __restrict__ gg,
    const float* __restrict__ bgn,
    float* __restrict__ out)
{
    const int lane = threadIdx.x & 63;
    const int c0 = lane & 15;
    const int g  = lane >> 4;
    const bf16x8* wp = (const bf16x8*)(S + OFF_WG);

    float bgv[4], ggv[4], bnv[4];
    #pragma unroll
    for (int nt = 0; nt < 4; ++nt) {
        bgv[nt] = bg[nt * 16 + c0];
        ggv[nt] = gg[nt * 16 + c0];
        bnv[nt] = bgn[nt * 16 + c0];
    }

    int wid = (blockIdx.x * 256 + threadIdx.x) >> 6;
    const int nwaves = (gridDim.x * 256) >> 6;
    for (int tile = wid; tile < NN / 16; tile += nwaves) {
        const int row0 = tile * 16;
        bf16x8 a[4];
        #pragma unroll
        for (int kt = 0; kt < 2; ++kt) {
            a[kt]     = *(const bf16x8*)&h2b[(size_t)(row0 + c0) * 64 + kt * 32 + g * 8];
            a[2 + kt] = *(const bf16x8*)&hnb[(size_t)(row0 + c0) * 64 + kt * 32 + g * 8];
        }
        f32x4 acc[4];
        #pragma unroll
        for (int nt = 0; nt < 4; ++nt) {
            float b = bgv[nt];
            f32x4 c = {b, b, b, b};
            #pragma unroll
            for (int kt = 0; kt < 4; ++kt)
                c = __builtin_amdgcn_mfma_f32_16x16x32_bf16(a[kt], wp[(nt * 4 + kt) * 64 + lane], c, 0, 0, 0);
            acc[nt] = c;
        }
        const int r0 = row0 + g * 4;
        #pragma unroll
        for (int r = 0; r < 4; ++r) {
            float rv[4];
            float s = 0.f;
            #pragma unroll
            for (int nt = 0; nt < 4; ++nt) {
                float hn = fmaxf(acc[nt][r], 0.f);
                rv[nt] = hn + b2f(h2b[(size_t)(r0 + r) * 64 + nt * 16 + c0]);
                s += rv[nt];
            }
            s = gsum16(s);
            float mu = s * (1.f / 64.f);
            float q = 0.f;
            #pragma unroll
            for (int nt = 0; nt < 4; ++nt) { float d = rv[nt] - mu; q += d * d; }
            q = gsum16(q);
            float inv = rsqrtf(q * (1.f / 64.f) + EPS);
            #pragma unroll
            for (int nt = 0; nt < 4; ++nt)
                out[(size_t)(r0 + r) * D + nt * 16 + c0] = (rv[nt] - mu) * inv * ggv[nt] + bnv[nt];
        }
    }
}

// ---------------- attention_samples passthrough (as fp32) ----------------
__global__ __launch_bounds__(256) void k_samples(
    const int* __restrict__ samp, float* __restrict__ out, int n)
{
    int i = blockIdx.x * blockDim.x + threadIdx.x;
    const int stride = gridDim.x * blockDim.x;
    for (; i < n; i += stride) out[i] = (float)samp[i];
}

extern "C" void kernel_launch(void* const* d_in, const int* in_sizes, int n_in,
                              void* d_out, int out_size, void* d_ws, size_t ws_size,
                              hipStream_t stream)
{
    const float* x   = (const float*)d_in[0];
    const int*   rows = (const int*)d_in[1];
    const int*   cols = (const int*)d_in[2];
    const float* ev  = (const float*)d_in[3];
    const int*   samp = (const int*)d_in[4];
    const float* Wq  = (const float*)d_in[5];
    const float* bq  = (const float*)d_in[6];
    const float* Wk  = (const float*)d_in[7];
    const float* bk  = (const float*)d_in[8];
    const float* Wv  = (const float*)d_in[9];
    const float* bv  = (const float*)d_in[10];
    const float* Wo  = (const float*)d_in[11];
    const float* bo  = (const float*)d_in[12];
    const float* g1  = (const float*)d_in[13];
    const float* be1 = (const float*)d_in[14];
    const float* g2  = (const float*)d_in[15];
    const float* be2 = (const float*)d_in[16];
    const float* W1  = (const float*)d_in[17];
    const float* bf1 = (const float*)d_in[18];
    const float* W2  = (const float*)d_in[19];
    const float* bf2 = (const float*)d_in[20];
    const float* Wg  = (const float*)d_in[21];
    const float* bg  = (const float*)d_in[22];
    const float* gg  = (const float*)d_in[23];
    const float* bgn = (const float*)d_in[24];
    const int E = in_sizes[1];
    const int npb = (E + PCHUNK - 1) / PCHUNK;

    // ws layout: 3 buffers of NN*D floats (76.8 MB)
    float* buf0 = (float*)d_ws;                   // KV8 (NN*128B) -> payload (uint[E])
    float* buf1 = buf0 + (size_t)NN * D;          // [Qp_b -> hnb_b | ob -> h2b] bf16
    float* buf2 = buf1 + (size_t)NN * D;          // hb fp32 -> part (int2[E])
    unsigned char* KV8 = (unsigned char*)buf0;                         // NN*128 bytes
    unsigned int* payload = (unsigned int*)buf0;       // overwrites KV8 after attn
    unsigned short* Qp_b  = (unsigned short*)buf1;     // dead after attn -> hnb slot
    unsigned short* hnb_b = (unsigned short*)buf1;
    unsigned short* ob    = (unsigned short*)(buf1 + (size_t)NN * D / 2); // dead after attno -> h2b slot
    unsigned short* h2b   = ob;
    float* hb = buf2;
    int2* part = (int2*)buf2;                          // overwrites hb after ffn

    float* out = (float*)d_out;
    // scratch in samples region of d_out (rewritten by k_samples each call; 8 MB available)
    short* S     = (short*)(out + (size_t)NN * D);   // S_TOTAL shorts
    int* offsets = (int*)(S + S_TOTAL);              // NN+1
    int* bbase   = offsets + NN + 1;                 // NB+1
    int* btot    = bbase + NB + 1;                   // NB
    int* partial = btot + NB;                        // npb*NB
    unsigned char* h2f4 = (unsigned char*)(partial + (size_t)npb * NB); // NN*32 bytes (3.2MB)

    k_prep<<<56, 256, 0, stream>>>(W1, W2, Wg, Wq, Wk, Wv, Wo, S);
    k_bhist<<<npb, 256, 0, stream>>>(rows, partial, E);
    k_pscan_a<<<NB, 256, 0, stream>>>(partial, btot, npb);
    k_pscan_b<<<1, 256, 0, stream>>>(btot, bbase, offsets);
    k_projqkv_mfma<<<1563, 256, 0, stream>>>(x, S, bq, bk, bv, Qp_b, KV8);
    k_attn_lite<<<4096, 256, 0, stream>>>(Qp_b, KV8, samp, ob);
    k_attno_mfma<<<1563, 256, 0, stream>>>(ob, x, S, bo, g1, be1, hb);
    k_ffn_mfma<<<1563, 256, 0, stream>>>(hb, S, bf1, bf2, g2, be2, h2b, h2f4);
    k_part<<<npb, 256, 0, stream>>>(rows, cols, ev, partial, bbase, part, E);
    k_fill2<<<NB, 256, 0, stream>>>(bbase, part, offsets, payload);
    k_gather<<<4096, 256, 0, stream>>>(offsets, payload, h2f4, hnb_b);
    k_gnn_mfma<<<1563, 256, 0, stream>>>(h2b, hnb_b, S, bg, gg, bgn, out);
    k_samples<<<2048, 256, 0, stream>>>(samp, out + (size_t)NN * D, NN * KS);
}

// Round 16
// 312.051 us; speedup vs baseline: 1.0220x; 1.0220x over previous
//
#include <hip/hip_runtime.h>
#include <hip/hip_bf16.h>

#define NN  100000
#define D   64
#define KS  20
#define DFF 256
#define EPS 1e-5f

// radix-partition params
#define BROWS  512
#define NB     ((NN + BROWS - 1) / BROWS)   // 196 buckets
#define PCHUNK 8192                          // edges per chunk (k_bhist & k_part)

// frag-buffer offsets (shorts)
#define OFF_W1 0
#define OFF_W2 16384
#define OFF_WG 32768
#define OFF_WQ 40960
#define OFF_WK 45056
#define OFF_WV 49152
#define OFF_WO 53248
#define S_TOTAL 57344

typedef __attribute__((ext_vector_type(8))) short bf16x8;
typedef __attribute__((ext_vector_type(4))) float f32x4;

__device__ __forceinline__ short f2b(float f) {
    return __builtin_bit_cast(short, __float2bfloat16(f));
}
__device__ __forceinline__ unsigned short f2bu(float f) {
    return __builtin_bit_cast(unsigned short, __float2bfloat16(f));
}
__device__ __forceinline__ float b2f(unsigned short u) {
    return __builtin_bit_cast(float, ((unsigned)u) << 16);
}
__device__ __forceinline__ unsigned char f2fp8(float v) {
    int p = __builtin_amdgcn_cvt_pk_fp8_f32(v, v, 0, false);
    return (unsigned char)(p & 0xFF);
}
__device__ __forceinline__ float gsum16(float v) {
    v += __shfl_xor(v, 1, 64);
    v += __shfl_xor(v, 2, 64);
    v += __shfl_xor(v, 4, 64);
    v += __shfl_xor(v, 8, 64);
    return v;
}

// ---------------- weight fragment prep (bf16, B-operand layout) ----------------
__global__ __launch_bounds__(256) void k_prep(
    const float* __restrict__ W1, const float* __restrict__ W2,
    const float* __restrict__ Wg,
    const float* __restrict__ Wq, const float* __restrict__ Wk,
    const float* __restrict__ Wv, const float* __restrict__ Wo,
    short* __restrict__ S)
{
    int idx = blockIdx.x * 256 + threadIdx.x;
    for (; idx < S_TOTAL; idx += gridDim.x * 256) {
        float v;
        if (idx < OFF_W2) {                 // W1 [64 x 256]
            int f = idx >> 9, rem = idx & 511;
            int l = rem >> 3, i = rem & 7;
            int nt = f >> 1, kt = f & 1;
            v = W1[(kt * 32 + (l >> 4) * 8 + i) * DFF + nt * 16 + (l & 15)];
        } else if (idx < OFF_WG) {          // W2 [256 x 64]
            int j = idx - OFF_W2;
            int f = j >> 9, rem = j & 511;
            int l = rem >> 3, i = rem & 7;
            int nt = f >> 3, kt = f & 7;
            v = W2[(kt * 32 + (l >> 4) * 8 + i) * D + nt * 16 + (l & 15)];
        } else if (idx < OFF_WQ) {          // Wg [128 x 64]
            int j = idx - OFF_WG;
            int f = j >> 9, rem = j & 511;
            int l = rem >> 3, i = rem & 7;
            int nt = f >> 2, kt = f & 3;
            v = Wg[(kt * 32 + (l >> 4) * 8 + i) * D + nt * 16 + (l & 15)];
        } else {                            // Wq/Wk/Wv/Wo [64 x 64]
            int j = idx - OFF_WQ;
            const float* W = (j < 4096) ? Wq : (j < 8192) ? Wk : (j < 12288) ? Wv : Wo;
            j &= 4095;
            int f = j >> 9, rem = j & 511;
            int l = rem >> 3, i = rem & 7;
            int nt = f >> 1, kt = f & 1;
            v = W[(kt * 32 + (l >> 4) * 8 + i) * D + nt * 16 + (l & 15)];
        }
        S[idx] = f2b(v);
    }
}

// ---------------- per-chunk bucket histogram (dense write, NO global atomics) ----------------
__global__ __launch_bounds__(256) void k_bhist(
    const int* __restrict__ rows, int* __restrict__ partial, int E)
{
    __shared__ int h[NB];
    for (int t = threadIdx.x; t < NB; t += 256) h[t] = 0;
    __syncthreads();
    const int i0 = blockIdx.x * PCHUNK;
    const int n = min(PCHUNK, E - i0);
    for (int t = threadIdx.x; t < n; t += 256)
        atomicAdd(&h[__builtin_nontemporal_load(rows + i0 + t) >> 9], 1);
    __syncthreads();
    for (int t = threadIdx.x; t < NB; t += 256)
        partial[blockIdx.x * NB + t] = h[t];
}

// ---------------- parallel 2D prefix, stage A: per-bucket scan over chunks ----------------
__global__ __launch_bounds__(256) void k_pscan_a(
    int* __restrict__ partial, int* __restrict__ btot, int npb)
{
    __shared__ int wsum[4];
    __shared__ int s_carry;
    const int b = blockIdx.x;
    const int tid = threadIdx.x;
    const int lane = tid & 63, wv = tid >> 6;
    if (tid == 0) s_carry = 0;
    __syncthreads();
    for (int base = 0; base < npb; base += 512) {
        int p0 = base + 2 * tid, p1 = p0 + 1;
        int c0 = (p0 < npb) ? partial[p0 * NB + b] : 0;
        int c1 = (p1 < npb) ? partial[p1 * NB + b] : 0;
        int s = c0 + c1;
        int sv = s;
        #pragma unroll
        for (int off = 1; off < 64; off <<= 1) {
            int u = __shfl_up(sv, off, 64);
            if (lane >= off) sv += u;
        }
        if (lane == 63) wsum[wv] = sv;
        __syncthreads();
        int wofs = 0;
        for (int k = 0; k < wv; ++k) wofs += wsum[k];
        int o0 = s_carry + wofs + sv - s;
        int o1 = o0 + c0;
        if (p0 < npb) partial[p0 * NB + b] = o0;
        if (p1 < npb) partial[p1 * NB + b] = o1;
        __syncthreads();
        if (tid == 0) s_carry += wsum[0] + wsum[1] + wsum[2] + wsum[3];
        __syncthreads();
    }
    if (tid == 0) btot[b] = s_carry;
}

// ---------------- stage B: bucket scan of totals -> bbase; offsets[NN]=E ----------------
__global__ __launch_bounds__(256) void k_pscan_b(
    const int* __restrict__ btot, int* __restrict__ bbase,
    int* __restrict__ offsets)
{
    __shared__ int wsum[4];
    const int t = threadIdx.x;
    const int lane = t & 63, wv = t >> 6;
    int v = (t < NB) ? btot[t] : 0;
    int sv = v;
    #pragma unroll
    for (int off = 1; off < 64; off <<= 1) {
        int u = __shfl_up(sv, off, 64);
        if (lane >= off) sv += u;
    }
    if (lane == 63) wsum[wv] = sv;
    __syncthreads();
    int wofs = 0;
    for (int k = 0; k < wv; ++k) wofs += wsum[k];
    int excl = wofs + sv - v;
    if (t < NB) bbase[t] = excl;
    if (t == 0) {
        int tot = wsum[0] + wsum[1] + wsum[2] + wsum[3];
        bbase[NB] = tot;
        offsets[NN] = tot;
    }
}

// ---------------- phase 1: radix-partition edges by bucket (row>>9) ----------------
__global__ __launch_bounds__(256) void k_part(
    const int* __restrict__ rows, const int* __restrict__ cols,
    const float* __restrict__ ev, const int* __restrict__ pbase,
    const int* __restrict__ bbase,
    int2* __restrict__ part, int E)
{
    __shared__ int base[NB];
    __shared__ int lcnt[NB];
    const int tid = threadIdx.x;
    const int i0 = blockIdx.x * PCHUNK;
    const int n = min(PCHUNK, E - i0);
    for (int t = tid; t < NB; t += 256) {
        base[t] = bbase[t] + pbase[blockIdx.x * NB + t];
        lcnt[t] = 0;
    }
    __syncthreads();
    for (int t = tid; t < n; t += 256) {
        int r = __builtin_nontemporal_load(rows + i0 + t);
        int c = __builtin_nontemporal_load(cols + i0 + t);
        float w = __builtin_nontemporal_load(ev + i0 + t);
        int b = r >> 9;
        int lpos = atomicAdd(&lcnt[b], 1);
        part[base[b] + lpos] = make_int2(((r & (BROWS - 1)) << 17) | c, __float_as_int(w));
    }
}

// ---------------- phase 2: in-bucket row offsets (LDS scan) + packed placement ----------------
// payload: (col << 15) | (bf16(w) & 0x7FFF)  -- w in [0,1) so sign bit is 0
__global__ __launch_bounds__(256) void k_fill2(
    const int* __restrict__ bbase, const int2* __restrict__ part,
    int* __restrict__ offsets, unsigned int* __restrict__ payload)
{
    __shared__ int lcnt[BROWS];
    __shared__ int lcur[BROWS];
    __shared__ int wsum[4];
    const int b = blockIdx.x;
    const int row0 = b * BROWS;
    const int nrows = min(BROWS, NN - row0);
    const int tid = threadIdx.x;
    for (int t = tid; t < BROWS; t += 256) lcnt[t] = 0;
    __syncthreads();
    const int e0 = bbase[b], e1 = bbase[b + 1];
    for (int i = e0 + tid; i < e1; i += 256)
        atomicAdd(&lcnt[(unsigned)part[i].x >> 17], 1);
    __syncthreads();
    int c0 = lcnt[2 * tid], c1 = lcnt[2 * tid + 1];
    int s = c0 + c1;
    const int lane = tid & 63, wv = tid >> 6;
    int sv = s;
    #pragma unroll
    for (int off = 1; off < 64; off <<= 1) {
        int u = __shfl_up(sv, off, 64);
        if (lane >= off) sv += u;
    }
    if (lane == 63) wsum[wv] = sv;
    __syncthreads();
    int wofs = 0;
    for (int k = 0; k < wv; ++k) wofs += wsum[k];
    int o0 = e0 + wofs + sv - s;
    int o1 = o0 + c0;
    lcur[2 * tid] = o0;
    lcur[2 * tid + 1] = o1;
    if (2 * tid < nrows)     offsets[row0 + 2 * tid]     = o0;
    if (2 * tid + 1 < nrows) offsets[row0 + 2 * tid + 1] = o1;
    __syncthreads();
    for (int i = e0 + tid; i < e1; i += 256) {
        int2 rec = part[i];
        int rowoff = (unsigned)rec.x >> 17;
        int pos = atomicAdd(&lcur[rowoff], 1);
        unsigned int col = (unsigned)(rec.x & 0x1FFFF);
        unsigned int wb = (unsigned)(f2bu(__int_as_float(rec.y)) & 0x7FFF);
        payload[pos] = (col << 15) | wb;
    }
}

// ---------------- segment gather-reduce (fp8 source, packed payload) ----------------
__global__ __launch_bounds__(256) void k_gather(
    const int* __restrict__ offsets, const unsigned int* __restrict__ payload,
    const unsigned char* __restrict__ h2f8, unsigned short* __restrict__ hnb)
{
    const int lane = threadIdx.x & 63;
    const int g = lane >> 4, c0 = lane & 15;
    int w = (blockIdx.x * 256 + threadIdx.x) >> 6;
    const int nw = (gridDim.x * 256) >> 6;
    for (int row = w; row < NN; row += nw) {
        const int b = offsets[row], e = offsets[row + 1];
        float ax = 0.f, ay = 0.f, az = 0.f, aw = 0.f;
        int i = b + g;
        for (; i + 4 < e; i += 8) {
            unsigned int p0 = __builtin_nontemporal_load(payload + i);
            unsigned int p1 = __builtin_nontemporal_load(payload + i + 4);
            float w0 = b2f((unsigned short)(p0 & 0x7FFF));
            float w1 = b2f((unsigned short)(p1 & 0x7FFF));
            const int u0 = *(const int*)(h2f8 + (size_t)(p0 >> 15) * 64 + c0 * 4);
            const int u1 = *(const int*)(h2f8 + (size_t)(p1 >> 15) * 64 + c0 * 4);
            ax = fmaf(__builtin_amdgcn_cvt_f32_fp8(u0, 0), w0, ax);
            ay = fmaf(__builtin_amdgcn_cvt_f32_fp8(u0, 1), w0, ay);
            az = fmaf(__builtin_amdgcn_cvt_f32_fp8(u0, 2), w0, az);
            aw = fmaf(__builtin_amdgcn_cvt_f32_fp8(u0, 3), w0, aw);
            ax = fmaf(__builtin_amdgcn_cvt_f32_fp8(u1, 0), w1, ax);
            ay = fmaf(__builtin_amdgcn_cvt_f32_fp8(u1, 1), w1, ay);
            az = fmaf(__builtin_amdgcn_cvt_f32_fp8(u1, 2), w1, az);
            aw = fmaf(__builtin_amdgcn_cvt_f32_fp8(u1, 3), w1, aw);
        }
        if (i < e) {
            unsigned int p = __builtin_nontemporal_load(payload + i);
            float wt = b2f((unsigned short)(p & 0x7FFF));
            const int u = *(const int*)(h2f8 + (size_t)(p >> 15) * 64 + c0 * 4);
            ax = fmaf(__builtin_amdgcn_cvt_f32_fp8(u, 0), wt, ax);
            ay = fmaf(__builtin_amdgcn_cvt_f32_fp8(u, 1), wt, ay);
            az = fmaf(__builtin_amdgcn_cvt_f32_fp8(u, 2), wt, az);
            aw = fmaf(__builtin_amdgcn_cvt_f32_fp8(u, 3), wt, aw);
        }
        ax += __shfl_xor(ax, 16, 64); ax += __shfl_xor(ax, 32, 64);
        ay += __shfl_xor(ay, 16, 64); ay += __shfl_xor(ay, 32, 64);
        az += __shfl_xor(az, 16, 64); az += __shfl_xor(az, 32, 64);
        aw += __shfl_xor(aw, 16, 64); aw += __shfl_xor(aw, 32, 64);
        if (g == 0) {
            ushort4 o;
            o.x = f2bu(ax); o.y = f2bu(ay); o.z = f2bu(az); o.w = f2bu(aw);
            *(ushort4*)(hnb + (size_t)row * 64 + c0 * 4) = o;
        }
    }
}

// ---------------- Q/K/V projection via MFMA -> Q bf16, KV interleaved fp8 ----------------
// KV8 row r: bytes [0..63] = K[r][0..63], bytes [64..127] = V[r][0..63]
__global__ __launch_bounds__(256) void k_projqkv_mfma(
    const float* __restrict__ x, const short* __restrict__ S,
    const float* __restrict__ bq, const float* __restrict__ bk,
    const float* __restrict__ bv,
    unsigned short* __restrict__ Qp, unsigned char* __restrict__ KV8)
{
    const int lane = threadIdx.x & 63;
    const int c0 = lane & 15;
    const int g  = lane >> 4;
    const bf16x8* wq = (const bf16x8*)(S + OFF_WQ);
    const bf16x8* wk = (const bf16x8*)(S + OFF_WK);
    const bf16x8* wv = (const bf16x8*)(S + OFF_WV);

    float bqv[4], bkv[4], bvv[4];
    #pragma unroll
    for (int nt = 0; nt < 4; ++nt) {
        bqv[nt] = bq[nt * 16 + c0];
        bkv[nt] = bk[nt * 16 + c0];
        bvv[nt] = bv[nt * 16 + c0];
    }

    int wid = (blockIdx.x * 256 + threadIdx.x) >> 6;
    const int nwaves = (gridDim.x * 256) >> 6;
    for (int tile = wid; tile < NN / 16; tile += nwaves) {
        const int row0 = tile * 16;
        const float* ar = x + (size_t)(row0 + c0) * D + g * 8;
        bf16x8 a0, a1;
        {
            float4 f0 = *(const float4*)(ar);
            float4 f1 = *(const float4*)(ar + 4);
            float4 f2 = *(const float4*)(ar + 32);
            float4 f3 = *(const float4*)(ar + 36);
            a0[0] = f2b(f0.x); a0[1] = f2b(f0.y); a0[2] = f2b(f0.z); a0[3] = f2b(f0.w);
            a0[4] = f2b(f1.x); a0[5] = f2b(f1.y); a0[6] = f2b(f1.z); a0[7] = f2b(f1.w);
            a1[0] = f2b(f2.x); a1[1] = f2b(f2.y); a1[2] = f2b(f2.z); a1[3] = f2b(f2.w);
            a1[4] = f2b(f3.x); a1[5] = f2b(f3.y); a1[6] = f2b(f3.z); a1[7] = f2b(f3.w);
        }
        f32x4 aq[4], ak[4], av[4];
        #pragma unroll
        for (int nt = 0; nt < 4; ++nt) {
            f32x4 cq = {bqv[nt], bqv[nt], bqv[nt], bqv[nt]};
            cq = __builtin_amdgcn_mfma_f32_16x16x32_bf16(a0, wq[(nt * 2 + 0) * 64 + lane], cq, 0, 0, 0);
            cq = __builtin_amdgcn_mfma_f32_16x16x32_bf16(a1, wq[(nt * 2 + 1) * 64 + lane], cq, 0, 0, 0);
            aq[nt] = cq;
            f32x4 ck = {bkv[nt], bkv[nt], bkv[nt], bkv[nt]};
            ck = __builtin_amdgcn_mfma_f32_16x16x32_bf16(a0, wk[(nt * 2 + 0) * 64 + lane], ck, 0, 0, 0);
            ck = __builtin_amdgcn_mfma_f32_16x16x32_bf16(a1, wk[(nt * 2 + 1) * 64 + lane], ck, 0, 0, 0);
            ak[nt] = ck;
            f32x4 cv = {bvv[nt], bvv[nt], bvv[nt], bvv[nt]};
            cv = __builtin_amdgcn_mfma_f32_16x16x32_bf16(a0, wv[(nt * 2 + 0) * 64 + lane], cv, 0, 0, 0);
            cv = __builtin_amdgcn_mfma_f32_16x16x32_bf16(a1, wv[(nt * 2 + 1) * 64 + lane], cv, 0, 0, 0);
            av[nt] = cv;
        }
        const int r0 = row0 + g * 4;
        #pragma unroll
        for (int r = 0; r < 4; ++r) {
            #pragma unroll
            for (int nt = 0; nt < 4; ++nt) {
                Qp[(size_t)(r0 + r) * D + nt * 16 + c0] = f2bu(aq[nt][r]);
                KV8[(size_t)(r0 + r) * 128 + nt * 16 + c0]      = f2fp8(ak[nt][r]);
                KV8[(size_t)(r0 + r) * 128 + 64 + nt * 16 + c0] = f2fp8(av[nt][r]);
            }
        }
    }
}

// ---------------- attention core: interleaved fp8 KV gathers + per-head softmax + PV ----------------
__global__ __launch_bounds__(256) void k_attn_lite(
    const unsigned short* __restrict__ Qp,
    const unsigned char* __restrict__ KV8,
    const int* __restrict__ samp, unsigned short* __restrict__ ob)
{
    const int lane = threadIdx.x & 63;
    const int g = lane >> 4, c0 = lane & 15;
    int w = (blockIdx.x * 256 + threadIdx.x) >> 6;
    const int nw = (gridDim.x * 256) >> 6;
    for (int row = w; row < NN; row += nw) {
        int idx_reg = (lane < KS) ? samp[row * KS + lane] : 0;
        const ushort4 qv = *(const ushort4*)(Qp + (size_t)row * D + c0 * 4);
        float q0 = b2f(qv.x), q1 = b2f(qv.y), q2 = b2f(qv.z), q3 = b2f(qv.w);

        float s[5];
        int v4[5];
        #pragma unroll
        for (int t = 0; t < 5; ++t) {
            int idx = __shfl(idx_reg, g * 5 + t, 64);
            const unsigned char* base = KV8 + (size_t)idx * 128 + c0 * 4;
            const int ku = *(const int*)(base);
            v4[t] = *(const int*)(base + 64);
            float sc = q0 * __builtin_amdgcn_cvt_f32_fp8(ku, 0);
            sc = fmaf(q1, __builtin_amdgcn_cvt_f32_fp8(ku, 1), sc);
            sc = fmaf(q2, __builtin_amdgcn_cvt_f32_fp8(ku, 2), sc);
            sc = fmaf(q3, __builtin_amdgcn_cvt_f32_fp8(ku, 3), sc);
            sc += __shfl_xor(sc, 1, 64);
            sc += __shfl_xor(sc, 2, 64);
            s[t] = sc * 0.25f;   // 1/sqrt(DH=16)
        }
        float m = fmaxf(fmaxf(fmaxf(s[0], s[1]), fmaxf(s[2], s[3])), s[4]);
        m = fmaxf(m, __shfl_xor(m, 16, 64));
        m = fmaxf(m, __shfl_xor(m, 32, 64));
        float o0 = 0.f, o1 = 0.f, o2 = 0.f, o3 = 0.f, ssum = 0.f;
        #pragma unroll
        for (int t = 0; t < 5; ++t) {
            float p = __expf(s[t] - m);
            ssum += p;
            o0 = fmaf(p, __builtin_amdgcn_cvt_f32_fp8(v4[t], 0), o0);
            o1 = fmaf(p, __builtin_amdgcn_cvt_f32_fp8(v4[t], 1), o1);
            o2 = fmaf(p, __builtin_amdgcn_cvt_f32_fp8(v4[t], 2), o2);
            o3 = fmaf(p, __builtin_amdgcn_cvt_f32_fp8(v4[t], 3), o3);
        }
        ssum += __shfl_xor(ssum, 16, 64);
        ssum += __shfl_xor(ssum, 32, 64);
        float inv = 1.0f / ssum;
        o0 += __shfl_xor(o0, 16, 64); o0 += __shfl_xor(o0, 32, 64);
        o1 += __shfl_xor(o1, 16, 64); o1 += __shfl_xor(o1, 32, 64);
        o2 += __shfl_xor(o2, 16, 64); o2 += __shfl_xor(o2, 32, 64);
        o3 += __shfl_xor(o3, 16, 64); o3 += __shfl_xor(o3, 32, 64);
        if (g == 0) {
            ushort4 o;
            o.x = f2bu(o0 * inv); o.y = f2bu(o1 * inv);
            o.z = f2bu(o2 * inv); o.w = f2bu(o3 * inv);
            *(ushort4*)(ob + (size_t)row * D + c0 * 4) = o;
        }
    }
}

// ---------------- Wo projection + residual + LN1 via MFMA -> hbb bf16 ----------------
__global__ __launch_bounds__(256) void k_attno_mfma(
    const unsigned short* __restrict__ ob, const float* __restrict__ x,
    const short* __restrict__ S,
    const float* __restrict__ bo, const float* __restrict__ g1,
    const float* __restrict__ be1,
    unsigned short* __restrict__ hbb)
{
    const int lane = threadIdx.x & 63;
    const int c0 = lane & 15;
    const int g  = lane >> 4;
    const bf16x8* wp = (const bf16x8*)(S + OFF_WO);

    float bov[4], g1v[4], b1v[4];
    #pragma unroll
    for (int nt = 0; nt < 4; ++nt) {
        bov[nt] = bo[nt * 16 + c0];
        g1v[nt] = g1[nt * 16 + c0];
        b1v[nt] = be1[nt * 16 + c0];
    }

    int wid = (blockIdx.x * 256 + threadIdx.x) >> 6;
    const int nwaves = (gridDim.x * 256) >> 6;
    for (int tile = wid; tile < NN / 16; tile += nwaves) {
        const int row0 = tile * 16;
        bf16x8 a[2];
        #pragma unroll
        for (int kt = 0; kt < 2; ++kt)
            a[kt] = *(const bf16x8*)&ob[(size_t)(row0 + c0) * D + kt * 32 + g * 8];
        f32x4 acc[4];
        #pragma unroll
        for (int nt = 0; nt < 4; ++nt) {
            f32x4 c = {bov[nt], bov[nt], bov[nt], bov[nt]};
            #pragma unroll
            for (int kt = 0; kt < 2; ++kt)
                c = __builtin_amdgcn_mfma_f32_16x16x32_bf16(a[kt], wp[(nt * 2 + kt) * 64 + lane], c, 0, 0, 0);
            acc[nt] = c;
        }
        const int r0 = row0 + g * 4;
        #pragma unroll
        for (int r = 0; r < 4; ++r) {
            float rv[4];
            float s = 0.f;
            #pragma unroll
            for (int nt = 0; nt < 4; ++nt) {
                rv[nt] = acc[nt][r] + x[(size_t)(r0 + r) * D + nt * 16 + c0];
                s += rv[nt];
            }
            s = gsum16(s);
            float mu = s * (1.f / 64.f);
            float q = 0.f;
            #pragma unroll
            for (int nt = 0; nt < 4; ++nt) { float d = rv[nt] - mu; q += d * d; }
            q = gsum16(q);
            float inv = rsqrtf(q * (1.f / 64.f) + EPS);
            #pragma unroll
            for (int nt = 0; nt < 4; ++nt)
                hbb[(size_t)(r0 + r) * D + nt * 16 + c0] = f2bu((rv[nt] - mu) * inv * g1v[nt] + b1v[nt]);
        }
    }
}

// ---------------- FFN via MFMA (bf16 hbb in) -> bf16 h2 + fp8 copy ----------------
__global__ __launch_bounds__(256) void k_ffn_mfma(
    const unsigned short* __restrict__ hbb,
    const short* __restrict__ wf,
    const float* __restrict__ bf1, const float* __restrict__ bf2,
    const float* __restrict__ g2, const float* __restrict__ be2,
    unsigned short* __restrict__ h2b, unsigned char* __restrict__ h2f8)
{
    __shared__ __align__(16) short Tl[4][16][264];
    const int lane = threadIdx.x & 63;
    const int wv   = threadIdx.x >> 6;
    const int c0   = lane & 15;
    const int g    = lane >> 4;
    const bf16x8* w1p = (const bf16x8*)(wf + OFF_W1);
    const bf16x8* w2p = (const bf16x8*)(wf + OFF_W2);

    float b1v[16];
    #pragma unroll
    for (int nt = 0; nt < 16; ++nt) b1v[nt] = bf1[nt * 16 + c0];
    float b2v[4], g2v[4], bev[4];
    #pragma unroll
    for (int nt = 0; nt < 4; ++nt) {
        b2v[nt] = bf2[nt * 16 + c0];
        g2v[nt] = g2[nt * 16 + c0];
        bev[nt] = be2[nt * 16 + c0];
    }

    int wid = (blockIdx.x * 256 + threadIdx.x) >> 6;
    const int nwaves = (gridDim.x * 256) >> 6;
    for (int tile = wid; tile < NN / 16; tile += nwaves) {
        const int row0 = tile * 16;
        bf16x8 a0 = *(const bf16x8*)&hbb[(size_t)(row0 + c0) * D + g * 8];
        bf16x8 a1 = *(const bf16x8*)&hbb[(size_t)(row0 + c0) * D + 32 + g * 8];
        f32x4 acc1[16];
        #pragma unroll
        for (int nt = 0; nt < 16; ++nt) {
            float b = b1v[nt];
            f32x4 c = {b, b, b, b};
            c = __builtin_amdgcn_mfma_f32_16x16x32_bf16(a0, w1p[(nt * 2 + 0) * 64 + lane], c, 0, 0, 0);
            c = __builtin_amdgcn_mfma_f32_16x16x32_bf16(a1, w1p[(nt * 2 + 1) * 64 + lane], c, 0, 0, 0);
            acc1[nt] = c;
        }
        #pragma unroll
        for (int nt = 0; nt < 16; ++nt) {
            #pragma unroll
            for (int r = 0; r < 4; ++r)
                Tl[wv][g * 4 + r][nt * 16 + c0] = f2b(fmaxf(acc1[nt][r], 0.f));
        }
        bf16x8 a2[8];
        #pragma unroll
        for (int kt = 0; kt < 8; ++kt)
            a2[kt] = *(const bf16x8*)&Tl[wv][c0][kt * 32 + g * 8];
        f32x4 acc2[4];
        #pragma unroll
        for (int nt = 0; nt < 4; ++nt) {
            float b = b2v[nt];
            f32x4 c = {b, b, b, b};
            #pragma unroll
            for (int kt = 0; kt < 8; ++kt)
                c = __builtin_amdgcn_mfma_f32_16x16x32_bf16(a2[kt], w2p[(nt * 8 + kt) * 64 + lane], c, 0, 0, 0);
            acc2[nt] = c;
        }
        const int r0 = row0 + g * 4;
        #pragma unroll
        for (int r = 0; r < 4; ++r) {
            float rv[4];
            float s = 0.f;
            #pragma unroll
            for (int nt = 0; nt < 4; ++nt) {
                rv[nt] = acc2[nt][r] + b2f(hbb[(size_t)(r0 + r) * D + nt * 16 + c0]);
                s += rv[nt];
            }
            s = gsum16(s);
            float mu = s * (1.f / 64.f);
            float q = 0.f;
            #pragma unroll
            for (int nt = 0; nt < 4; ++nt) { float d = rv[nt] - mu; q += d * d; }
            q = gsum16(q);
            float inv = rsqrtf(q * (1.f / 64.f) + EPS);
            #pragma unroll
            for (int nt = 0; nt < 4; ++nt) {
                float hv = (rv[nt] - mu) * inv * g2v[nt] + bev[nt];
                h2b[(size_t)(r0 + r) * D + nt * 16 + c0] = f2bu(hv);
                h2f8[(size_t)(r0 + r) * D + nt * 16 + c0] = f2fp8(hv);
            }
        }
    }
}

// ---------------- GNN linear (MFMA, bf16 inputs) + relu + residual + LN -> fp32 out ----------------
__global__ __launch_bounds__(256) void k_gnn_mfma(
    const unsigned short* __restrict__ h2b, const unsigned short* __restrict__ hnb,
    const short* __restrict__ S,
    const float* __restrict__ bg, const float* __restrict__ gg,
    const float* __restrict__ bgn,
    float* __restrict__ out)
{
    const int lane = threadIdx.x & 63;
    const int c0 = lane & 15;
    const int g  = lane >> 4;
    const bf16x8* wp = (const bf16x8*)(S + OFF_WG);

    float bgv[4], ggv[4], bnv[4];
    #pragma unroll
    for (int nt = 0; nt < 4; ++nt) {
        bgv[nt] = bg[nt * 16 + c0];
        ggv[nt] = gg[nt * 16 + c0];
        bnv[nt] = bgn[nt * 16 + c0];
    }

    int wid = (blockIdx.x * 256 + threadIdx.x) >> 6;
    const int nwaves = (gridDim.x * 256) >> 6;
    for (int tile = wid; tile < NN / 16; tile += nwaves) {
        const int row0 = tile * 16;
        bf16x8 a[4];
        #pragma unroll
        for (int kt = 0; kt < 2; ++kt) {
            a[kt]     = *(const bf16x8*)&h2b[(size_t)(row0 + c0) * 64 + kt * 32 + g * 8];
            a[2 + kt] = *(const bf16x8*)&hnb[(size_t)(row0 + c0) * 64 + kt * 32 + g * 8];
        }
        f32x4 acc[4];
        #pragma unroll
        for (int nt = 0; nt < 4; ++nt) {
            float b = bgv[nt];
            f32x4 c = {b, b, b, b};
            #pragma unroll
            for (int kt = 0; kt < 4; ++kt)
                c = __builtin_amdgcn_mfma_f32_16x16x32_bf16(a[kt], wp[(nt * 4 + kt) * 64 + lane], c, 0, 0, 0);
            acc[nt] = c;
        }
        const int r0 = row0 + g * 4;
        #pragma unroll
        for (int r = 0; r < 4; ++r) {
            float rv[4];
            float s = 0.f;
            #pragma unroll
            for (int nt = 0; nt < 4; ++nt) {
                float hn = fmaxf(acc[nt][r], 0.f);
                rv[nt] = hn + b2f(h2b[(size_t)(r0 + r) * 64 + nt * 16 + c0]);
                s += rv[nt];
            }
            s = gsum16(s);
            float mu = s * (1.f / 64.f);
            float q = 0.f;
            #pragma unroll
            for (int nt = 0; nt < 4; ++nt) { float d = rv[nt] - mu; q += d * d; }
            q = gsum16(q);
            float inv = rsqrtf(q * (1.f / 64.f) + EPS);
            #pragma unroll
            for (int nt = 0; nt < 4; ++nt)
                out[(size_t)(r0 + r) * D + nt * 16 + c0] = (rv[nt] - mu) * inv * ggv[nt] + bnv[nt];
        }
    }
}

// ---------------- attention_samples passthrough (as fp32) ----------------
__global__ __launch_bounds__(256) void k_samples(
    const int* __restrict__ samp, float* __restrict__ out, int n)
{
    int i = blockIdx.x * blockDim.x + threadIdx.x;
    const int stride = gridDim.x * blockDim.x;
    for (; i < n; i += stride) out[i] = (float)samp[i];
}

extern "C" void kernel_launch(void* const* d_in, const int* in_sizes, int n_in,
                              void* d_out, int out_size, void* d_ws, size_t ws_size,
                              hipStream_t stream)
{
    const float* x   = (const float*)d_in[0];
    const int*   rows = (const int*)d_in[1];
    const int*   cols = (const int*)d_in[2];
    const float* ev  = (const float*)d_in[3];
    const int*   samp = (const int*)d_in[4];
    const float* Wq  = (const float*)d_in[5];
    const float* bq  = (const float*)d_in[6];
    const float* Wk  = (const float*)d_in[7];
    const float* bk  = (const float*)d_in[8];
    const float* Wv  = (const float*)d_in[9];
    const float* bv  = (const float*)d_in[10];
    const float* Wo  = (const float*)d_in[11];
    const float* bo  = (const float*)d_in[12];
    const float* g1  = (const float*)d_in[13];
    const float* be1 = (const float*)d_in[14];
    const float* g2  = (const float*)d_in[15];
    const float* be2 = (const float*)d_in[16];
    const float* W1  = (const float*)d_in[17];
    const float* bf1 = (const float*)d_in[18];
    const float* W2  = (const float*)d_in[19];
    const float* bf2 = (const float*)d_in[20];
    const float* Wg  = (const float*)d_in[21];
    const float* bg  = (const float*)d_in[22];
    const float* gg  = (const float*)d_in[23];
    const float* bgn = (const float*)d_in[24];
    const int E = in_sizes[1];
    const int npb = (E + PCHUNK - 1) / PCHUNK;

    // ws layout: 3 buffers of NN*D floats (76.8 MB)
    float* buf0 = (float*)d_ws;                   // KV8 (NN*128B) -> payload (uint[E])
    float* buf1 = buf0 + (size_t)NN * D;          // [Qp_b -> hnb_b | ob -> h2b] bf16
    float* buf2 = buf1 + (size_t)NN * D;          // hbb bf16 -> part (int2[E])
    unsigned char* KV8 = (unsigned char*)buf0;                         // NN*128 bytes
    unsigned int* payload = (unsigned int*)buf0;       // overwrites KV8 after attn
    unsigned short* Qp_b  = (unsigned short*)buf1;     // dead after attn -> hnb slot
    unsigned short* hnb_b = (unsigned short*)buf1;
    unsigned short* ob    = (unsigned short*)(buf1 + (size_t)NN * D / 2); // dead after attno -> h2b slot
    unsigned short* h2b   = ob;
    unsigned short* hbb = (unsigned short*)buf2;       // bf16; dead after ffn -> part slot
    int2* part = (int2*)buf2;                          // overwrites hbb after ffn

    float* out = (float*)d_out;
    // scratch in samples region of d_out (rewritten by k_samples each call; 8 MB available)
    short* S     = (short*)(out + (size_t)NN * D);   // S_TOTAL shorts
    int* offsets = (int*)(S + S_TOTAL);              // NN+1
    int* bbase   = offsets + NN + 1;                 // NB+1
    int* btot    = bbase + NB + 1;                   // NB
    int* partial = btot + NB;                        // npb*NB
    unsigned char* h2f8 = (unsigned char*)(partial + (size_t)npb * NB); // NN*64 bytes (6.4MB)

    k_prep<<<56, 256, 0, stream>>>(W1, W2, Wg, Wq, Wk, Wv, Wo, S);
    k_bhist<<<npb, 256, 0, stream>>>(rows, partial, E);
    k_pscan_a<<<NB, 256, 0, stream>>>(partial, btot, npb);
    k_pscan_b<<<1, 256, 0, stream>>>(btot, bbase, offsets);
    k_projqkv_mfma<<<1563, 256, 0, stream>>>(x, S, bq, bk, bv, Qp_b, KV8);
    k_attn_lite<<<4096, 256, 0, stream>>>(Qp_b, KV8, samp, ob);
    k_attno_mfma<<<1563, 256, 0, stream>>>(ob, x, S, bo, g1, be1, hbb);
    k_ffn_mfma<<<1563, 256, 0, stream>>>(hbb, S, bf1, bf2, g2, be2, h2b, h2f8);
    k_part<<<npb, 256, 0, stream>>>(rows, cols, ev, partial, bbase, part, E);
    k_fill2<<<NB, 256, 0, stream>>>(bbase, part, offsets, payload);
    k_gather<<<4096, 256, 0, stream>>>(offsets, payload, h2f8, hnb_b);
    k_gnn_mfma<<<1563, 256, 0, stream>>>(h2b, hnb_b, S, bg, gg, bgn, out);
    k_samples<<<2048, 256, 0, stream>>>(samp, out + (size_t)NN * D, NN * KS);
}

// Round 17
// 300.426 us; speedup vs baseline: 1.0616x; 1.0387x over previous
//
#include <hip/hip_runtime.h>
#include <hip/hip_bf16.h>

#define NN  100000
#define D   64
#define KS  20
#define DFF 256
#define EPS 1e-5f

// radix-partition params
#define BROWS  512
#define NB     ((NN + BROWS - 1) / BROWS)   // 196 buckets
#define PCHUNK 8192                          // edges per chunk (k_bhist & k_part)

// frag-buffer offsets (shorts)
#define OFF_W1 0
#define OFF_W2 16384
#define OFF_WG 32768
#define OFF_WQ 40960
#define OFF_WK 45056
#define OFF_WV 49152
#define OFF_WO 53248
#define S_TOTAL 57344

typedef __attribute__((ext_vector_type(8))) short bf16x8;
typedef __attribute__((ext_vector_type(4))) float f32x4;

__device__ __forceinline__ short f2b(float f) {
    return __builtin_bit_cast(short, __float2bfloat16(f));
}
__device__ __forceinline__ unsigned short f2bu(float f) {
    return __builtin_bit_cast(unsigned short, __float2bfloat16(f));
}
__device__ __forceinline__ float b2f(unsigned short u) {
    return __builtin_bit_cast(float, ((unsigned)u) << 16);
}
__device__ __forceinline__ unsigned char f2fp8(float v) {
    int p = __builtin_amdgcn_cvt_pk_fp8_f32(v, v, 0, false);
    return (unsigned char)(p & 0xFF);
}
__device__ __forceinline__ float gsum16(float v) {
    v += __shfl_xor(v, 1, 64);
    v += __shfl_xor(v, 2, 64);
    v += __shfl_xor(v, 4, 64);
    v += __shfl_xor(v, 8, 64);
    return v;
}

// ---------------- weight fragment prep (bf16, B-operand layout) ----------------
__global__ __launch_bounds__(256) void k_prep(
    const float* __restrict__ W1, const float* __restrict__ W2,
    const float* __restrict__ Wg,
    const float* __restrict__ Wq, const float* __restrict__ Wk,
    const float* __restrict__ Wv, const float* __restrict__ Wo,
    short* __restrict__ S)
{
    int idx = blockIdx.x * 256 + threadIdx.x;
    for (; idx < S_TOTAL; idx += gridDim.x * 256) {
        float v;
        if (idx < OFF_W2) {                 // W1 [64 x 256]
            int f = idx >> 9, rem = idx & 511;
            int l = rem >> 3, i = rem & 7;
            int nt = f >> 1, kt = f & 1;
            v = W1[(kt * 32 + (l >> 4) * 8 + i) * DFF + nt * 16 + (l & 15)];
        } else if (idx < OFF_WG) {          // W2 [256 x 64]
            int j = idx - OFF_W2;
            int f = j >> 9, rem = j & 511;
            int l = rem >> 3, i = rem & 7;
            int nt = f >> 3, kt = f & 7;
            v = W2[(kt * 32 + (l >> 4) * 8 + i) * D + nt * 16 + (l & 15)];
        } else if (idx < OFF_WQ) {          // Wg [128 x 64]
            int j = idx - OFF_WG;
            int f = j >> 9, rem = j & 511;
            int l = rem >> 3, i = rem & 7;
            int nt = f >> 2, kt = f & 3;
            v = Wg[(kt * 32 + (l >> 4) * 8 + i) * D + nt * 16 + (l & 15)];
        } else {                            // Wq/Wk/Wv/Wo [64 x 64]
            int j = idx - OFF_WQ;
            const float* W = (j < 4096) ? Wq : (j < 8192) ? Wk : (j < 12288) ? Wv : Wo;
            j &= 4095;
            int f = j >> 9, rem = j & 511;
            int l = rem >> 3, i = rem & 7;
            int nt = f >> 1, kt = f & 1;
            v = W[(kt * 32 + (l >> 4) * 8 + i) * D + nt * 16 + (l & 15)];
        }
        S[idx] = f2b(v);
    }
}

// ---------------- per-chunk bucket histogram (dense write, NO global atomics) ----------------
__global__ __launch_bounds__(256) void k_bhist(
    const int* __restrict__ rows, int* __restrict__ partial, int E)
{
    __shared__ int h[NB];
    for (int t = threadIdx.x; t < NB; t += 256) h[t] = 0;
    __syncthreads();
    const int i0 = blockIdx.x * PCHUNK;
    const int n = min(PCHUNK, E - i0);
    for (int t = threadIdx.x; t < n; t += 256)
        atomicAdd(&h[__builtin_nontemporal_load(rows + i0 + t) >> 9], 1);
    __syncthreads();
    for (int t = threadIdx.x; t < NB; t += 256)
        partial[blockIdx.x * NB + t] = h[t];
}

// ---------------- parallel 2D prefix, stage A: per-bucket scan over chunks ----------------
__global__ __launch_bounds__(256) void k_pscan_a(
    int* __restrict__ partial, int* __restrict__ btot, int npb)
{
    __shared__ int wsum[4];
    __shared__ int s_carry;
    const int b = blockIdx.x;
    const int tid = threadIdx.x;
    const int lane = tid & 63, wv = tid >> 6;
    if (tid == 0) s_carry = 0;
    __syncthreads();
    for (int base = 0; base < npb; base += 512) {
        int p0 = base + 2 * tid, p1 = p0 + 1;
        int c0 = (p0 < npb) ? partial[p0 * NB + b] : 0;
        int c1 = (p1 < npb) ? partial[p1 * NB + b] : 0;
        int s = c0 + c1;
        int sv = s;
        #pragma unroll
        for (int off = 1; off < 64; off <<= 1) {
            int u = __shfl_up(sv, off, 64);
            if (lane >= off) sv += u;
        }
        if (lane == 63) wsum[wv] = sv;
        __syncthreads();
        int wofs = 0;
        for (int k = 0; k < wv; ++k) wofs += wsum[k];
        int o0 = s_carry + wofs + sv - s;
        int o1 = o0 + c0;
        if (p0 < npb) partial[p0 * NB + b] = o0;
        if (p1 < npb) partial[p1 * NB + b] = o1;
        __syncthreads();
        if (tid == 0) s_carry += wsum[0] + wsum[1] + wsum[2] + wsum[3];
        __syncthreads();
    }
    if (tid == 0) btot[b] = s_carry;
}

// ---------------- stage B: bucket scan of totals -> bbase; offsets[NN]=E ----------------
__global__ __launch_bounds__(256) void k_pscan_b(
    const int* __restrict__ btot, int* __restrict__ bbase,
    int* __restrict__ offsets)
{
    __shared__ int wsum[4];
    const int t = threadIdx.x;
    const int lane = t & 63, wv = t >> 6;
    int v = (t < NB) ? btot[t] : 0;
    int sv = v;
    #pragma unroll
    for (int off = 1; off < 64; off <<= 1) {
        int u = __shfl_up(sv, off, 64);
        if (lane >= off) sv += u;
    }
    if (lane == 63) wsum[wv] = sv;
    __syncthreads();
    int wofs = 0;
    for (int k = 0; k < wv; ++k) wofs += wsum[k];
    int excl = wofs + sv - v;
    if (t < NB) bbase[t] = excl;
    if (t == 0) {
        int tot = wsum[0] + wsum[1] + wsum[2] + wsum[3];
        bbase[NB] = tot;
        offsets[NN] = tot;
    }
}

// ---------------- phase 1: radix-partition edges by bucket (row>>9) ----------------
__global__ __launch_bounds__(256) void k_part(
    const int* __restrict__ rows, const int* __restrict__ cols,
    const float* __restrict__ ev, const int* __restrict__ pbase,
    const int* __restrict__ bbase,
    int2* __restrict__ part, int E)
{
    __shared__ int base[NB];
    __shared__ int lcnt[NB];
    const int tid = threadIdx.x;
    const int i0 = blockIdx.x * PCHUNK;
    const int n = min(PCHUNK, E - i0);
    for (int t = tid; t < NB; t += 256) {
        base[t] = bbase[t] + pbase[blockIdx.x * NB + t];
        lcnt[t] = 0;
    }
    __syncthreads();
    for (int t = tid; t < n; t += 256) {
        int r = __builtin_nontemporal_load(rows + i0 + t);
        int c = __builtin_nontemporal_load(cols + i0 + t);
        float w = __builtin_nontemporal_load(ev + i0 + t);
        int b = r >> 9;
        int lpos = atomicAdd(&lcnt[b], 1);
        part[base[b] + lpos] = make_int2(((r & (BROWS - 1)) << 17) | c, __float_as_int(w));
    }
}

// ---------------- phase 2: in-bucket row offsets (LDS scan) + packed placement ----------------
// payload: (col << 15) | (bf16(w) & 0x7FFF)  -- w in [0,1) so sign bit is 0
__global__ __launch_bounds__(256) void k_fill2(
    const int* __restrict__ bbase, const int2* __restrict__ part,
    int* __restrict__ offsets, unsigned int* __restrict__ payload)
{
    __shared__ int lcnt[BROWS];
    __shared__ int lcur[BROWS];
    __shared__ int wsum[4];
    const int b = blockIdx.x;
    const int row0 = b * BROWS;
    const int nrows = min(BROWS, NN - row0);
    const int tid = threadIdx.x;
    for (int t = tid; t < BROWS; t += 256) lcnt[t] = 0;
    __syncthreads();
    const int e0 = bbase[b], e1 = bbase[b + 1];
    for (int i = e0 + tid; i < e1; i += 256)
        atomicAdd(&lcnt[(unsigned)part[i].x >> 17], 1);
    __syncthreads();
    int c0 = lcnt[2 * tid], c1 = lcnt[2 * tid + 1];
    int s = c0 + c1;
    const int lane = tid & 63, wv = tid >> 6;
    int sv = s;
    #pragma unroll
    for (int off = 1; off < 64; off <<= 1) {
        int u = __shfl_up(sv, off, 64);
        if (lane >= off) sv += u;
    }
    if (lane == 63) wsum[wv] = sv;
    __syncthreads();
    int wofs = 0;
    for (int k = 0; k < wv; ++k) wofs += wsum[k];
    int o0 = e0 + wofs + sv - s;
    int o1 = o0 + c0;
    lcur[2 * tid] = o0;
    lcur[2 * tid + 1] = o1;
    if (2 * tid < nrows)     offsets[row0 + 2 * tid]     = o0;
    if (2 * tid + 1 < nrows) offsets[row0 + 2 * tid + 1] = o1;
    __syncthreads();
    for (int i = e0 + tid; i < e1; i += 256) {
        int2 rec = part[i];
        int rowoff = (unsigned)rec.x >> 17;
        int pos = atomicAdd(&lcur[rowoff], 1);
        unsigned int col = (unsigned)(rec.x & 0x1FFFF);
        unsigned int wb = (unsigned)(f2bu(__int_as_float(rec.y)) & 0x7FFF);
        payload[pos] = (col << 15) | wb;
    }
}

// ---------------- segment gather-reduce (fp8 source, packed payload) ----------------
__global__ __launch_bounds__(256) void k_gather(
    const int* __restrict__ offsets, const unsigned int* __restrict__ payload,
    const unsigned char* __restrict__ h2f8, unsigned short* __restrict__ hnb)
{
    const int lane = threadIdx.x & 63;
    const int g = lane >> 4, c0 = lane & 15;
    int w = (blockIdx.x * 256 + threadIdx.x) >> 6;
    const int nw = (gridDim.x * 256) >> 6;
    for (int row = w; row < NN; row += nw) {
        const int b = offsets[row], e = offsets[row + 1];
        float ax = 0.f, ay = 0.f, az = 0.f, aw = 0.f;
        int i = b + g;
        for (; i + 4 < e; i += 8) {
            unsigned int p0 = payload[i];
            unsigned int p1 = payload[i + 4];
            float w0 = b2f((unsigned short)(p0 & 0x7FFF));
            float w1 = b2f((unsigned short)(p1 & 0x7FFF));
            const int u0 = *(const int*)(h2f8 + (size_t)(p0 >> 15) * 64 + c0 * 4);
            const int u1 = *(const int*)(h2f8 + (size_t)(p1 >> 15) * 64 + c0 * 4);
            ax = fmaf(__builtin_amdgcn_cvt_f32_fp8(u0, 0), w0, ax);
            ay = fmaf(__builtin_amdgcn_cvt_f32_fp8(u0, 1), w0, ay);
            az = fmaf(__builtin_amdgcn_cvt_f32_fp8(u0, 2), w0, az);
            aw = fmaf(__builtin_amdgcn_cvt_f32_fp8(u0, 3), w0, aw);
            ax = fmaf(__builtin_amdgcn_cvt_f32_fp8(u1, 0), w1, ax);
            ay = fmaf(__builtin_amdgcn_cvt_f32_fp8(u1, 1), w1, ay);
            az = fmaf(__builtin_amdgcn_cvt_f32_fp8(u1, 2), w1, az);
            aw = fmaf(__builtin_amdgcn_cvt_f32_fp8(u1, 3), w1, aw);
        }
        if (i < e) {
            unsigned int p = payload[i];
            float wt = b2f((unsigned short)(p & 0x7FFF));
            const int u = *(const int*)(h2f8 + (size_t)(p >> 15) * 64 + c0 * 4);
            ax = fmaf(__builtin_amdgcn_cvt_f32_fp8(u, 0), wt, ax);
            ay = fmaf(__builtin_amdgcn_cvt_f32_fp8(u, 1), wt, ay);
            az = fmaf(__builtin_amdgcn_cvt_f32_fp8(u, 2), wt, az);
            aw = fmaf(__builtin_amdgcn_cvt_f32_fp8(u, 3), wt, aw);
        }
        ax += __shfl_xor(ax, 16, 64); ax += __shfl_xor(ax, 32, 64);
        ay += __shfl_xor(ay, 16, 64); ay += __shfl_xor(ay, 32, 64);
        az += __shfl_xor(az, 16, 64); az += __shfl_xor(az, 32, 64);
        aw += __shfl_xor(aw, 16, 64); aw += __shfl_xor(aw, 32, 64);
        if (g == 0) {
            ushort4 o;
            o.x = f2bu(ax); o.y = f2bu(ay); o.z = f2bu(az); o.w = f2bu(aw);
            *(ushort4*)(hnb + (size_t)row * 64 + c0 * 4) = o;
        }
    }
}

// ---------------- Q/K/V projection via MFMA -> Q bf16, KV interleaved fp8 ----------------
// KV8 row r: bytes [0..63] = K[r][0..63], bytes [64..127] = V[r][0..63]
__global__ __launch_bounds__(256) void k_projqkv_mfma(
    const float* __restrict__ x, const short* __restrict__ S,
    const float* __restrict__ bq, const float* __restrict__ bk,
    const float* __restrict__ bv,
    unsigned short* __restrict__ Qp, unsigned char* __restrict__ KV8)
{
    const int lane = threadIdx.x & 63;
    const int c0 = lane & 15;
    const int g  = lane >> 4;
    const bf16x8* wq = (const bf16x8*)(S + OFF_WQ);
    const bf16x8* wk = (const bf16x8*)(S + OFF_WK);
    const bf16x8* wv = (const bf16x8*)(S + OFF_WV);

    float bqv[4], bkv[4], bvv[4];
    #pragma unroll
    for (int nt = 0; nt < 4; ++nt) {
        bqv[nt] = bq[nt * 16 + c0];
        bkv[nt] = bk[nt * 16 + c0];
        bvv[nt] = bv[nt * 16 + c0];
    }

    int wid = (blockIdx.x * 256 + threadIdx.x) >> 6;
    const int nwaves = (gridDim.x * 256) >> 6;
    for (int tile = wid; tile < NN / 16; tile += nwaves) {
        const int row0 = tile * 16;
        const float* ar = x + (size_t)(row0 + c0) * D + g * 8;
        bf16x8 a0, a1;
        {
            float4 f0 = *(const float4*)(ar);
            float4 f1 = *(const float4*)(ar + 4);
            float4 f2 = *(const float4*)(ar + 32);
            float4 f3 = *(const float4*)(ar + 36);
            a0[0] = f2b(f0.x); a0[1] = f2b(f0.y); a0[2] = f2b(f0.z); a0[3] = f2b(f0.w);
            a0[4] = f2b(f1.x); a0[5] = f2b(f1.y); a0[6] = f2b(f1.z); a0[7] = f2b(f1.w);
            a1[0] = f2b(f2.x); a1[1] = f2b(f2.y); a1[2] = f2b(f2.z); a1[3] = f2b(f2.w);
            a1[4] = f2b(f3.x); a1[5] = f2b(f3.y); a1[6] = f2b(f3.z); a1[7] = f2b(f3.w);
        }
        f32x4 aq[4], ak[4], av[4];
        #pragma unroll
        for (int nt = 0; nt < 4; ++nt) {
            f32x4 cq = {bqv[nt], bqv[nt], bqv[nt], bqv[nt]};
            cq = __builtin_amdgcn_mfma_f32_16x16x32_bf16(a0, wq[(nt * 2 + 0) * 64 + lane], cq, 0, 0, 0);
            cq = __builtin_amdgcn_mfma_f32_16x16x32_bf16(a1, wq[(nt * 2 + 1) * 64 + lane], cq, 0, 0, 0);
            aq[nt] = cq;
            f32x4 ck = {bkv[nt], bkv[nt], bkv[nt], bkv[nt]};
            ck = __builtin_amdgcn_mfma_f32_16x16x32_bf16(a0, wk[(nt * 2 + 0) * 64 + lane], ck, 0, 0, 0);
            ck = __builtin_amdgcn_mfma_f32_16x16x32_bf16(a1, wk[(nt * 2 + 1) * 64 + lane], ck, 0, 0, 0);
            ak[nt] = ck;
            f32x4 cv = {bvv[nt], bvv[nt], bvv[nt], bvv[nt]};
            cv = __builtin_amdgcn_mfma_f32_16x16x32_bf16(a0, wv[(nt * 2 + 0) * 64 + lane], cv, 0, 0, 0);
            cv = __builtin_amdgcn_mfma_f32_16x16x32_bf16(a1, wv[(nt * 2 + 1) * 64 + lane], cv, 0, 0, 0);
            av[nt] = cv;
        }
        const int r0 = row0 + g * 4;
        #pragma unroll
        for (int r = 0; r < 4; ++r) {
            #pragma unroll
            for (int nt = 0; nt < 4; ++nt) {
                Qp[(size_t)(r0 + r) * D + nt * 16 + c0] = f2bu(aq[nt][r]);
                KV8[(size_t)(r0 + r) * 128 + nt * 16 + c0]      = f2fp8(ak[nt][r]);
                KV8[(size_t)(r0 + r) * 128 + 64 + nt * 16 + c0] = f2fp8(av[nt][r]);
            }
        }
    }
}

// ---------------- attention core: interleaved fp8 KV gathers + per-head softmax + PV ----------------
__global__ __launch_bounds__(256) void k_attn_lite(
    const unsigned short* __restrict__ Qp,
    const unsigned char* __restrict__ KV8,
    const int* __restrict__ samp, unsigned short* __restrict__ ob)
{
    const int lane = threadIdx.x & 63;
    const int g = lane >> 4, c0 = lane & 15;
    int w = (blockIdx.x * 256 + threadIdx.x) >> 6;
    const int nw = (gridDim.x * 256) >> 6;
    for (int row = w; row < NN; row += nw) {
        int idx_reg = (lane < KS) ? samp[row * KS + lane] : 0;
        const ushort4 qv = *(const ushort4*)(Qp + (size_t)row * D + c0 * 4);
        float q0 = b2f(qv.x), q1 = b2f(qv.y), q2 = b2f(qv.z), q3 = b2f(qv.w);

        float s[5];
        int v4[5];
        #pragma unroll
        for (int t = 0; t < 5; ++t) {
            int idx = __shfl(idx_reg, g * 5 + t, 64);
            const unsigned char* base = KV8 + (size_t)idx * 128 + c0 * 4;
            const int ku = *(const int*)(base);
            v4[t] = *(const int*)(base + 64);
            float sc = q0 * __builtin_amdgcn_cvt_f32_fp8(ku, 0);
            sc = fmaf(q1, __builtin_amdgcn_cvt_f32_fp8(ku, 1), sc);
            sc = fmaf(q2, __builtin_amdgcn_cvt_f32_fp8(ku, 2), sc);
            sc = fmaf(q3, __builtin_amdgcn_cvt_f32_fp8(ku, 3), sc);
            sc += __shfl_xor(sc, 1, 64);
            sc += __shfl_xor(sc, 2, 64);
            s[t] = sc * 0.25f;   // 1/sqrt(DH=16)
        }
        float m = fmaxf(fmaxf(fmaxf(s[0], s[1]), fmaxf(s[2], s[3])), s[4]);
        m = fmaxf(m, __shfl_xor(m, 16, 64));
        m = fmaxf(m, __shfl_xor(m, 32, 64));
        float o0 = 0.f, o1 = 0.f, o2 = 0.f, o3 = 0.f, ssum = 0.f;
        #pragma unroll
        for (int t = 0; t < 5; ++t) {
            float p = __expf(s[t] - m);
            ssum += p;
            o0 = fmaf(p, __builtin_amdgcn_cvt_f32_fp8(v4[t], 0), o0);
            o1 = fmaf(p, __builtin_amdgcn_cvt_f32_fp8(v4[t], 1), o1);
            o2 = fmaf(p, __builtin_amdgcn_cvt_f32_fp8(v4[t], 2), o2);
            o3 = fmaf(p, __builtin_amdgcn_cvt_f32_fp8(v4[t], 3), o3);
        }
        ssum += __shfl_xor(ssum, 16, 64);
        ssum += __shfl_xor(ssum, 32, 64);
        float inv = 1.0f / ssum;
        o0 += __shfl_xor(o0, 16, 64); o0 += __shfl_xor(o0, 32, 64);
        o1 += __shfl_xor(o1, 16, 64); o1 += __shfl_xor(o1, 32, 64);
        o2 += __shfl_xor(o2, 16, 64); o2 += __shfl_xor(o2, 32, 64);
        o3 += __shfl_xor(o3, 16, 64); o3 += __shfl_xor(o3, 32, 64);
        if (g == 0) {
            ushort4 o;
            o.x = f2bu(o0 * inv); o.y = f2bu(o1 * inv);
            o.z = f2bu(o2 * inv); o.w = f2bu(o3 * inv);
            *(ushort4*)(ob + (size_t)row * D + c0 * 4) = o;
        }
    }
}

// ---------------- Wo projection + residual + LN1 via MFMA -> hbb bf16 ----------------
__global__ __launch_bounds__(256) void k_attno_mfma(
    const unsigned short* __restrict__ ob, const float* __restrict__ x,
    const short* __restrict__ S,
    const float* __restrict__ bo, const float* __restrict__ g1,
    const float* __restrict__ be1,
    unsigned short* __restrict__ hbb)
{
    const int lane = threadIdx.x & 63;
    const int c0 = lane & 15;
    const int g  = lane >> 4;
    const bf16x8* wp = (const bf16x8*)(S + OFF_WO);

    float bov[4], g1v[4], b1v[4];
    #pragma unroll
    for (int nt = 0; nt < 4; ++nt) {
        bov[nt] = bo[nt * 16 + c0];
        g1v[nt] = g1[nt * 16 + c0];
        b1v[nt] = be1[nt * 16 + c0];
    }

    int wid = (blockIdx.x * 256 + threadIdx.x) >> 6;
    const int nwaves = (gridDim.x * 256) >> 6;
    for (int tile = wid; tile < NN / 16; tile += nwaves) {
        const int row0 = tile * 16;
        bf16x8 a[2];
        #pragma unroll
        for (int kt = 0; kt < 2; ++kt)
            a[kt] = *(const bf16x8*)&ob[(size_t)(row0 + c0) * D + kt * 32 + g * 8];
        f32x4 acc[4];
        #pragma unroll
        for (int nt = 0; nt < 4; ++nt) {
            f32x4 c = {bov[nt], bov[nt], bov[nt], bov[nt]};
            #pragma unroll
            for (int kt = 0; kt < 2; ++kt)
                c = __builtin_amdgcn_mfma_f32_16x16x32_bf16(a[kt], wp[(nt * 2 + kt) * 64 + lane], c, 0, 0, 0);
            acc[nt] = c;
        }
        const int r0 = row0 + g * 4;
        #pragma unroll
        for (int r = 0; r < 4; ++r) {
            float rv[4];
            float s = 0.f;
            #pragma unroll
            for (int nt = 0; nt < 4; ++nt) {
                rv[nt] = acc[nt][r] + x[(size_t)(r0 + r) * D + nt * 16 + c0];
                s += rv[nt];
            }
            s = gsum16(s);
            float mu = s * (1.f / 64.f);
            float q = 0.f;
            #pragma unroll
            for (int nt = 0; nt < 4; ++nt) { float d = rv[nt] - mu; q += d * d; }
            q = gsum16(q);
            float inv = rsqrtf(q * (1.f / 64.f) + EPS);
            #pragma unroll
            for (int nt = 0; nt < 4; ++nt)
                hbb[(size_t)(r0 + r) * D + nt * 16 + c0] = f2bu((rv[nt] - mu) * inv * g1v[nt] + b1v[nt]);
        }
    }
}

// ---------------- FFN via MFMA (bf16 hbb in) -> bf16 h2 + fp8 copy ----------------
__global__ __launch_bounds__(256) void k_ffn_mfma(
    const unsigned short* __restrict__ hbb,
    const short* __restrict__ wf,
    const float* __restrict__ bf1, const float* __restrict__ bf2,
    const float* __restrict__ g2, const float* __restrict__ be2,
    unsigned short* __restrict__ h2b, unsigned char* __restrict__ h2f8)
{
    __shared__ __align__(16) short Tl[4][16][264];
    const int lane = threadIdx.x & 63;
    const int wv   = threadIdx.x >> 6;
    const int c0   = lane & 15;
    const int g    = lane >> 4;
    const bf16x8* w1p = (const bf16x8*)(wf + OFF_W1);
    const bf16x8* w2p = (const bf16x8*)(wf + OFF_W2);

    float b1v[16];
    #pragma unroll
    for (int nt = 0; nt < 16; ++nt) b1v[nt] = bf1[nt * 16 + c0];
    float b2v[4], g2v[4], bev[4];
    #pragma unroll
    for (int nt = 0; nt < 4; ++nt) {
        b2v[nt] = bf2[nt * 16 + c0];
        g2v[nt] = g2[nt * 16 + c0];
        bev[nt] = be2[nt * 16 + c0];
    }

    int wid = (blockIdx.x * 256 + threadIdx.x) >> 6;
    const int nwaves = (gridDim.x * 256) >> 6;
    for (int tile = wid; tile < NN / 16; tile += nwaves) {
        const int row0 = tile * 16;
        bf16x8 a0 = *(const bf16x8*)&hbb[(size_t)(row0 + c0) * D + g * 8];
        bf16x8 a1 = *(const bf16x8*)&hbb[(size_t)(row0 + c0) * D + 32 + g * 8];
        f32x4 acc1[16];
        #pragma unroll
        for (int nt = 0; nt < 16; ++nt) {
            float b = b1v[nt];
            f32x4 c = {b, b, b, b};
            c = __builtin_amdgcn_mfma_f32_16x16x32_bf16(a0, w1p[(nt * 2 + 0) * 64 + lane], c, 0, 0, 0);
            c = __builtin_amdgcn_mfma_f32_16x16x32_bf16(a1, w1p[(nt * 2 + 1) * 64 + lane], c, 0, 0, 0);
            acc1[nt] = c;
        }
        #pragma unroll
        for (int nt = 0; nt < 16; ++nt) {
            #pragma unroll
            for (int r = 0; r < 4; ++r)
                Tl[wv][g * 4 + r][nt * 16 + c0] = f2b(fmaxf(acc1[nt][r], 0.f));
        }
        bf16x8 a2[8];
        #pragma unroll
        for (int kt = 0; kt < 8; ++kt)
            a2[kt] = *(const bf16x8*)&Tl[wv][c0][kt * 32 + g * 8];
        f32x4 acc2[4];
        #pragma unroll
        for (int nt = 0; nt < 4; ++nt) {
            float b = b2v[nt];
            f32x4 c = {b, b, b, b};
            #pragma unroll
            for (int kt = 0; kt < 8; ++kt)
                c = __builtin_amdgcn_mfma_f32_16x16x32_bf16(a2[kt], w2p[(nt * 8 + kt) * 64 + lane], c, 0, 0, 0);
            acc2[nt] = c;
        }
        const int r0 = row0 + g * 4;
        #pragma unroll
        for (int r = 0; r < 4; ++r) {
            float rv[4];
            float s = 0.f;
            #pragma unroll
            for (int nt = 0; nt < 4; ++nt) {
                rv[nt] = acc2[nt][r] + b2f(hbb[(size_t)(r0 + r) * D + nt * 16 + c0]);
                s += rv[nt];
            }
            s = gsum16(s);
            float mu = s * (1.f / 64.f);
            float q = 0.f;
            #pragma unroll
            for (int nt = 0; nt < 4; ++nt) { float d = rv[nt] - mu; q += d * d; }
            q = gsum16(q);
            float inv = rsqrtf(q * (1.f / 64.f) + EPS);
            #pragma unroll
            for (int nt = 0; nt < 4; ++nt) {
                float hv = (rv[nt] - mu) * inv * g2v[nt] + bev[nt];
                h2b[(size_t)(r0 + r) * D + nt * 16 + c0] = f2bu(hv);
                h2f8[(size_t)(r0 + r) * D + nt * 16 + c0] = f2fp8(hv);
            }
        }
    }
}

// ---------------- GNN linear (MFMA, bf16 inputs) + relu + residual + LN -> fp32 out ----------------
__global__ __launch_bounds__(256) void k_gnn_mfma(
    const unsigned short* __restrict__ h2b, const unsigned short* __restrict__ hnb,
    const short* __restrict__ S,
    const float* __restrict__ bg, const float* __restrict__ gg,
    const float* __restrict__ bgn,
    float* __restrict__ out)
{
    const int lane = threadIdx.x & 63;
    const int c0 = lane & 15;
    const int g  = lane >> 4;
    const bf16x8* wp = (const bf16x8*)(S + OFF_WG);

    float bgv[4], ggv[4], bnv[4];
    #pragma unroll
    for (int nt = 0; nt < 4; ++nt) {
        bgv[nt] = bg[nt * 16 + c0];
        ggv[nt] = gg[nt * 16 + c0];
        bnv[nt] = bgn[nt * 16 + c0];
    }

    int wid = (blockIdx.x * 256 + threadIdx.x) >> 6;
    const int nwaves = (gridDim.x * 256) >> 6;
    for (int tile = wid; tile < NN / 16; tile += nwaves) {
        const int row0 = tile * 16;
        bf16x8 a[4];
        #pragma unroll
        for (int kt = 0; kt < 2; ++kt) {
            a[kt]     = *(const bf16x8*)&h2b[(size_t)(row0 + c0) * 64 + kt * 32 + g * 8];
            a[2 + kt] = *(const bf16x8*)&hnb[(size_t)(row0 + c0) * 64 + kt * 32 + g * 8];
        }
        f32x4 acc[4];
        #pragma unroll
        for (int nt = 0; nt < 4; ++nt) {
            float b = bgv[nt];
            f32x4 c = {b, b, b, b};
            #pragma unroll
            for (int kt = 0; kt < 4; ++kt)
                c = __builtin_amdgcn_mfma_f32_16x16x32_bf16(a[kt], wp[(nt * 4 + kt) * 64 + lane], c, 0, 0, 0);
            acc[nt] = c;
        }
        const int r0 = row0 + g * 4;
        #pragma unroll
        for (int r = 0; r < 4; ++r) {
            float rv[4];
            float s = 0.f;
            #pragma unroll
            for (int nt = 0; nt < 4; ++nt) {
                float hn = fmaxf(acc[nt][r], 0.f);
                rv[nt] = hn + b2f(h2b[(size_t)(r0 + r) * 64 + nt * 16 + c0]);
                s += rv[nt];
            }
            s = gsum16(s);
            float mu = s * (1.f / 64.f);
            float q = 0.f;
            #pragma unroll
            for (int nt = 0; nt < 4; ++nt) { float d = rv[nt] - mu; q += d * d; }
            q = gsum16(q);
            float inv = rsqrtf(q * (1.f / 64.f) + EPS);
            #pragma unroll
            for (int nt = 0; nt < 4; ++nt)
                out[(size_t)(r0 + r) * D + nt * 16 + c0] = (rv[nt] - mu) * inv * ggv[nt] + bnv[nt];
        }
    }
}

// ---------------- attention_samples passthrough (as fp32) ----------------
__global__ __launch_bounds__(256) void k_samples(
    const int* __restrict__ samp, float* __restrict__ out, int n)
{
    int i = blockIdx.x * blockDim.x + threadIdx.x;
    const int stride = gridDim.x * blockDim.x;
    for (; i < n; i += stride) out[i] = (float)samp[i];
}

extern "C" void kernel_launch(void* const* d_in, const int* in_sizes, int n_in,
                              void* d_out, int out_size, void* d_ws, size_t ws_size,
                              hipStream_t stream)
{
    const float* x   = (const float*)d_in[0];
    const int*   rows = (const int*)d_in[1];
    const int*   cols = (const int*)d_in[2];
    const float* ev  = (const float*)d_in[3];
    const int*   samp = (const int*)d_in[4];
    const float* Wq  = (const float*)d_in[5];
    const float* bq  = (const float*)d_in[6];
    const float* Wk  = (const float*)d_in[7];
    const float* bk  = (const float*)d_in[8];
    const float* Wv  = (const float*)d_in[9];
    const float* bv  = (const float*)d_in[10];
    const float* Wo  = (const float*)d_in[11];
    const float* bo  = (const float*)d_in[12];
    const float* g1  = (const float*)d_in[13];
    const float* be1 = (const float*)d_in[14];
    const float* g2  = (const float*)d_in[15];
    const float* be2 = (const float*)d_in[16];
    const float* W1  = (const float*)d_in[17];
    const float* bf1 = (const float*)d_in[18];
    const float* W2  = (const float*)d_in[19];
    const float* bf2 = (const float*)d_in[20];
    const float* Wg  = (const float*)d_in[21];
    const float* bg  = (const float*)d_in[22];
    const float* gg  = (const float*)d_in[23];
    const float* bgn = (const float*)d_in[24];
    const int E = in_sizes[1];
    const int npb = (E + PCHUNK - 1) / PCHUNK;

    // ws layout: 3 buffers of NN*D floats (76.8 MB)
    float* buf0 = (float*)d_ws;                   // KV8 (NN*128B) -> payload (uint[E])
    float* buf1 = buf0 + (size_t)NN * D;          // [Qp_b -> hnb_b | ob -> h2b] bf16
    float* buf2 = buf1 + (size_t)NN * D;          // hbb bf16 -> part (int2[E])
    unsigned char* KV8 = (unsigned char*)buf0;                         // NN*128 bytes
    unsigned int* payload = (unsigned int*)buf0;       // overwrites KV8 after attn
    unsigned short* Qp_b  = (unsigned short*)buf1;     // dead after attn -> hnb slot
    unsigned short* hnb_b = (unsigned short*)buf1;
    unsigned short* ob    = (unsigned short*)(buf1 + (size_t)NN * D / 2); // dead after attno -> h2b slot
    unsigned short* h2b   = ob;
    unsigned short* hbb = (unsigned short*)buf2;       // bf16; dead after ffn -> part slot
    int2* part = (int2*)buf2;                          // overwrites hbb after ffn

    float* out = (float*)d_out;
    // scratch in samples region of d_out (rewritten by k_samples each call; 8 MB available)
    short* S     = (short*)(out + (size_t)NN * D);   // S_TOTAL shorts
    int* offsets = (int*)(S + S_TOTAL);              // NN+1
    int* bbase   = offsets + NN + 1;                 // NB+1
    int* btot    = bbase + NB + 1;                   // NB
    int* partial = btot + NB;                        // npb*NB
    unsigned char* h2f8 = (unsigned char*)(partial + (size_t)npb * NB); // NN*64 bytes (6.4MB)

    k_prep<<<56, 256, 0, stream>>>(W1, W2, Wg, Wq, Wk, Wv, Wo, S);
    k_bhist<<<npb, 256, 0, stream>>>(rows, partial, E);
    k_pscan_a<<<NB, 256, 0, stream>>>(partial, btot, npb);
    k_pscan_b<<<1, 256, 0, stream>>>(btot, bbase, offsets);
    k_projqkv_mfma<<<1563, 256, 0, stream>>>(x, S, bq, bk, bv, Qp_b, KV8);
    k_attn_lite<<<4096, 256, 0, stream>>>(Qp_b, KV8, samp, ob);
    k_attno_mfma<<<1563, 256, 0, stream>>>(ob, x, S, bo, g1, be1, hbb);
    k_ffn_mfma<<<1563, 256, 0, stream>>>(hbb, S, bf1, bf2, g2, be2, h2b, h2f8);
    k_part<<<npb, 256, 0, stream>>>(rows, cols, ev, partial, bbase, part, E);
    k_fill2<<<NB, 256, 0, stream>>>(bbase, part, offsets, payload);
    k_gather<<<4096, 256, 0, stream>>>(offsets, payload, h2f8, hnb_b);
    k_gnn_mfma<<<1563, 256, 0, stream>>>(h2b, hnb_b, S, bg, gg, bgn, out);
    k_samples<<<2048, 256, 0, stream>>>(samp, out + (size_t)NN * D, NN * KS);
}